// Round 1
// baseline (2042.427 us; speedup 1.0000x reference)
//
#include <hip/hip_runtime.h>

#define HW 3136
#define DHW 50176
#define NEL 25690112   // 8*64*16*56*56
#define CNT 401408.0f  // 8*16*56*56

typedef __attribute__((ext_vector_type(8))) short          short8;
typedef __attribute__((ext_vector_type(8))) unsigned short ushort8;
typedef __attribute__((ext_vector_type(4))) float          f32x4;

__device__ __forceinline__ unsigned f2bf(float f) {
    union { float f; unsigned u; } v; v.f = f;
    return (v.u + 0x7FFFu + ((v.u >> 16) & 1u)) >> 16;   // RNE
}
__device__ __forceinline__ float bf2f(unsigned u) {
    union { unsigned u; float f; } v; v.u = u << 16;
    return v.f;
}

// ---------------------------------------------------------------------------
// x (fp32 NCDHW) -> xt (bf16 channels-last [n][d][h][w][ci])
// ---------------------------------------------------------------------------
__global__ __launch_bounds__(256) void k_transpose(
    const float* __restrict__ x, unsigned short* __restrict__ xt)
{
    __shared__ unsigned lds[4][64 * 36];
    const int d = blockIdx.x, n = blockIdx.y, z = blockIdx.z;
    const int wave = threadIdx.x >> 6, lane = threadIdx.x & 63;
    const float* xb = x + (size_t)n * 64 * DHW + d * HW;
    unsigned short* xtb = xt + (size_t)(n * 16 + d) * HW * 64;
    unsigned* L = lds[wave];

    for (int c = z * 7 + wave; c < z * 7 + 7 && c < 49; c += 4) {
        const int P = c * 64;
#pragma unroll 4
        for (int cp = 0; cp < 32; ++cp) {
            const float a = xb[(size_t)(2 * cp) * DHW + P + lane];
            const float b = xb[(size_t)(2 * cp + 1) * DHW + P + lane];
            L[lane * 36 + cp] = f2bf(a) | (f2bf(b) << 16);
        }
#pragma unroll
        for (int k = 0; k < 8; ++k) {
            const int r = (lane >> 3) + 8 * k;
            const uint4 v = *(const uint4*)&L[r * 36 + 4 * (lane & 7)];
            *(uint4*)((char*)xtb + (size_t)P * 128 + lane * 16 + k * 1024) = v;
        }
    }
}

// ---------------------------------------------------------------------------
// Weight prep: BtO[27][16(8 real)][64], Bt1/Bt2[27][64][64]  (bf16)
// ---------------------------------------------------------------------------
__global__ __launch_bounds__(256) void k_wprep(
    const float* __restrict__ w_off, const float* __restrict__ w1,
    const float* __restrict__ w2, unsigned short* __restrict__ BtO,
    unsigned short* __restrict__ Bt1, unsigned short* __restrict__ Bt2)
{
    const int i = blockIdx.x * 256 + threadIdx.x;
    if (i < 27648) {
        const int t = i / 1024, r = i - t * 1024, nn = r >> 6, k = r & 63;
        BtO[i] = (nn < 8) ? (unsigned short)f2bf(w_off[(nn * 64 + k) * 27 + t]) : 0;
    }
    if (i < 110592) {
        const int t = i / 4096, r = i - t * 4096, co = r >> 6, ci = r & 63;
        Bt1[i] = (unsigned short)f2bf(w1[(co * 64 + ci) * 27 + t]);
        Bt2[i] = (unsigned short)f2bf(w2[(co * 64 + ci) * 27 + t]);
    }
}

// ---------------------------------------------------------------------------
// Standard 3x3x3 conv via MFMA, LDS-staged. Block = (h, d, n), 256 thr.
// Used only for the 8-channel offset conv (NCO=8). 56-px rows, 75 KiB LDS.
// ---------------------------------------------------------------------------
template<int NCO, bool BN>
__global__ __launch_bounds__(256) void k_conv(
    const unsigned short* __restrict__ src, const unsigned short* __restrict__ Bt,
    const float* __restrict__ bias, const float* __restrict__ scv,
    const float* __restrict__ shv, float* __restrict__ dst)
{
    __shared__ unsigned short A[538 * 72];   // 9*58=522 slots + 16 overrun pad
    const int h = blockIdx.x, d = blockIdx.y, n = blockIdx.z;
    const int tid = threadIdx.x;
    const int wave = tid >> 6, lane = tid & 63, lm = lane & 15, quad = lane >> 4;
    const int k8 = tid & 7;                  // fixed ci-chunk per thread

    float scr[8], shr[8];
    if constexpr (BN) {
#pragma unroll
        for (int e = 0; e < 8; ++e) { scr[e] = scv[k8 * 8 + e]; shr[e] = shv[k8 * 8 + e]; }
    }

    const unsigned short* snb = src + (size_t)(n * 16) * HW * 64;

    // ---- stage 4176 16B chunks ----
    for (int c = tid; c < 4176; c += 256) {
        const int idx = c >> 3;
        const int row = idx / 58, px = idx - row * 58;
        const int kd = row / 3, kh = row - kd * 3;
        const int dq = d + kd - 1, hq = h + kh - 1, wq = px - 1;
        ushort8 val = (ushort8)0;
        if (((unsigned)dq < 16u) & ((unsigned)hq < 56u) & ((unsigned)wq < 56u)) {
            val = *(const ushort8*)(snb + ((size_t)dq * HW + hq * 56 + wq) * 64 + k8 * 8);
            if constexpr (BN) {
#pragma unroll
                for (int e = 0; e < 8; ++e) {
                    const float f = fmaxf(fmaf(bf2f(val[e]), scr[e], shr[e]), 0.f);
                    val[e] = (unsigned short)f2bf(f);
                }
            }
        }
        *(ushort8*)&A[(size_t)idx * 72 + k8 * 8] = val;
    }
    __syncthreads();

    constexpr int NB  = (NCO == 8) ? 16 : 64;
    constexpr int NFm = (NCO == 8) ? 1 : 2;
    constexpr int NFn = (NCO == 8) ? 1 : 2;
    const int mf0 = (NCO == 8) ? wave : (wave & 1) * 2;
    const int nf0 = (NCO == 8) ? 0 : (wave >> 1) * 2;

    f32x4 acc[NFm][NFn];
#pragma unroll
    for (int i = 0; i < NFm; ++i)
#pragma unroll
        for (int j = 0; j < NFn; ++j) acc[i][j] = (f32x4){0.f, 0.f, 0.f, 0.f};

    // ---- 27-tap K-loop, B software-pipelined ----
    short8 bc[2][NFn];
#pragma unroll
    for (int ks = 0; ks < 2; ++ks)
#pragma unroll
        for (int nf = 0; nf < NFn; ++nf)
            bc[ks][nf] = *(const short8*)(Bt + ((size_t)0 * NB + (nf0 + nf) * 16 + lm) * 64 + ks * 32 + quad * 8);

#pragma unroll 1
    for (int t = 0; t < 27; ++t) {
        short8 bnx[2][NFn];
        if (t < 26) {
#pragma unroll
            for (int ks = 0; ks < 2; ++ks)
#pragma unroll
                for (int nf = 0; nf < NFn; ++nf)
                    bnx[ks][nf] = *(const short8*)(Bt + ((size_t)(t + 1) * NB + (nf0 + nf) * 16 + lm) * 64 + ks * 32 + quad * 8);
        }
        const int kd = t / 9, r9 = t - kd * 9, kh = r9 / 3, kw = r9 - kh * 3;
        const int rowb = (kd * 3 + kh) * 58 + kw;
        short8 a[2][NFm];
#pragma unroll
        for (int ks = 0; ks < 2; ++ks)
#pragma unroll
            for (int mf = 0; mf < NFm; ++mf)
                a[ks][mf] = *(const short8*)&A[(size_t)(rowb + (mf0 + mf) * 16 + lm) * 72 + ks * 32 + quad * 8];
#pragma unroll
        for (int ks = 0; ks < 2; ++ks)
#pragma unroll
            for (int mf = 0; mf < NFm; ++mf)
#pragma unroll
                for (int nf = 0; nf < NFn; ++nf)
                    acc[mf][nf] = __builtin_amdgcn_mfma_f32_16x16x32_bf16(a[ks][mf], bc[ks][nf], acc[mf][nf], 0, 0, 0);
        if (t < 26) {
#pragma unroll
            for (int ks = 0; ks < 2; ++ks)
#pragma unroll
                for (int nf = 0; nf < NFn; ++nf)
                    bc[ks][nf] = bnx[ks][nf];
        }
    }

    // ---- epilogue: LDS transpose -> fp32 NCDHW + bias ----
    __syncthreads();
    float* E = (float*)A;
    constexpr int CSTR = (NCO == 64) ? 65 : 17;
#pragma unroll
    for (int mf = 0; mf < NFm; ++mf)
#pragma unroll
        for (int nf = 0; nf < NFn; ++nf)
#pragma unroll
            for (int r = 0; r < 4; ++r) {
                const int mm = (mf0 + mf) * 16 + quad * 4 + r;
                if (mm < 56) E[mm * CSTR + (nf0 + nf) * 16 + lm] = acc[mf][nf][r];
            }
    __syncthreads();
    for (int f = tid; f < 56 * NCO; f += 256) {
        const int co = f / 56, w0 = f - co * 56;
        dst[((size_t)(n * NCO + co) * 16 + d) * HW + h * 56 + w0] = E[w0 * CSTR + co] + bias[co];
    }
}

// ---------------------------------------------------------------------------
// conv2 (64->64) with fused input-BN+ReLU -- W-SPLIT version: each block does
// a 28-px half row. A-tile: 9 rows x 30 px x 64 ci @ stride 72 = 40320 B LDS
// -> 4 blocks/CU (vs 2 at the 56-px tile) -> 16 waves/CU. Latency-bound
// kernel, so occupancy is the lever. Each wave: 1 m-frag x 2 n-frags.
// ---------------------------------------------------------------------------
__global__ __launch_bounds__(256) void k_conv64(
    const unsigned short* __restrict__ src, const unsigned short* __restrict__ Bt,
    const float* __restrict__ bias, const float* __restrict__ scv,
    const float* __restrict__ shv, float* __restrict__ dst)
{
    __shared__ unsigned short A[280 * 72];   // 270 slots + 10 overrun pad = 40320 B
    const int h = blockIdx.x >> 1, wblk = (blockIdx.x & 1) * 28;
    const int d = blockIdx.y, n = blockIdx.z;
    const int tid = threadIdx.x;
    const int wave = tid >> 6, lane = tid & 63, lm = lane & 15, quad = lane >> 4;
    const int k8 = tid & 7;

    float scr[8], shr[8];
#pragma unroll
    for (int e = 0; e < 8; ++e) { scr[e] = scv[k8 * 8 + e]; shr[e] = shv[k8 * 8 + e]; }

    const unsigned short* snb = src + (size_t)(n * 16) * HW * 64;

    // ---- stage 280 slots x 8 chunks = 2240 (rows >= 9 are the zero pad) ----
    for (int c = tid; c < 2240; c += 256) {
        const int idx = c >> 3;
        const int row = idx / 30, px = idx - row * 30;
        const int kd = row / 3, kh = row - kd * 3;
        const int dq = d + kd - 1, hq = h + kh - 1, wq = wblk + px - 1;
        ushort8 val = (ushort8)0;
        if ((row < 9) & ((unsigned)dq < 16u) & ((unsigned)hq < 56u) & ((unsigned)wq < 56u)) {
            val = *(const ushort8*)(snb + ((size_t)dq * HW + hq * 56 + wq) * 64 + k8 * 8);
#pragma unroll
            for (int e = 0; e < 8; ++e) {
                const float f = fmaxf(fmaf(bf2f(val[e]), scr[e], shr[e]), 0.f);
                val[e] = (unsigned short)f2bf(f);
            }
        }
        *(ushort8*)&A[(size_t)idx * 72 + k8 * 8] = val;
    }
    __syncthreads();

    const int mf0 = wave & 1, nf0 = (wave >> 1) * 2;
    f32x4 acc[2];
    acc[0] = (f32x4){0.f, 0.f, 0.f, 0.f};
    acc[1] = (f32x4){0.f, 0.f, 0.f, 0.f};

    short8 bc[2][2];
#pragma unroll
    for (int ks = 0; ks < 2; ++ks)
#pragma unroll
        for (int nf = 0; nf < 2; ++nf)
            bc[ks][nf] = *(const short8*)(Bt + ((size_t)0 * 64 + (nf0 + nf) * 16 + lm) * 64 + ks * 32 + quad * 8);

#pragma unroll 1
    for (int t = 0; t < 27; ++t) {
        short8 bnx[2][2];
        if (t < 26) {
#pragma unroll
            for (int ks = 0; ks < 2; ++ks)
#pragma unroll
                for (int nf = 0; nf < 2; ++nf)
                    bnx[ks][nf] = *(const short8*)(Bt + ((size_t)(t + 1) * 64 + (nf0 + nf) * 16 + lm) * 64 + ks * 32 + quad * 8);
        }
        const int kd = t / 9, r9 = t - kd * 9, kh = r9 / 3, kw = r9 - kh * 3;
        const int rowb = (kd * 3 + kh) * 30 + kw;
        const unsigned short* ap = &A[(size_t)(rowb + mf0 * 16 + lm) * 72 + quad * 8];
        const short8 a0 = *(const short8*)(ap);
        const short8 a1 = *(const short8*)(ap + 32);
        acc[0] = __builtin_amdgcn_mfma_f32_16x16x32_bf16(a0, bc[0][0], acc[0], 0, 0, 0);
        acc[1] = __builtin_amdgcn_mfma_f32_16x16x32_bf16(a0, bc[0][1], acc[1], 0, 0, 0);
        acc[0] = __builtin_amdgcn_mfma_f32_16x16x32_bf16(a1, bc[1][0], acc[0], 0, 0, 0);
        acc[1] = __builtin_amdgcn_mfma_f32_16x16x32_bf16(a1, bc[1][1], acc[1], 0, 0, 0);
        if (t < 26) {
#pragma unroll
            for (int ks = 0; ks < 2; ++ks)
#pragma unroll
                for (int nf = 0; nf < 2; ++nf)
                    bc[ks][nf] = bnx[ks][nf];
        }
    }

    // ---- epilogue: LDS transpose -> fp32 NCDHW + bias ----
    __syncthreads();
    float* E = (float*)A;                    // 28 x 65 floats = 7280 B
#pragma unroll
    for (int nf = 0; nf < 2; ++nf)
#pragma unroll
        for (int r = 0; r < 4; ++r) {
            const int mm = mf0 * 16 + quad * 4 + r;
            if (mm < 28) E[mm * 65 + (nf0 + nf) * 16 + lm] = acc[nf][r];
        }
    __syncthreads();
    for (int f = tid; f < 1792; f += 256) {
        const int co = f / 28, w0 = f - co * 28;
        dst[((size_t)(n * 64 + co) * 16 + d) * HW + h * 56 + wblk + w0] = E[w0 * 65 + co] + bias[co];
    }
}

// ---------------------------------------------------------------------------
// Temporal deformable conv -- W-SPLIT version (28-px half rows, 40320 B LDS,
// 4 blocks/CU). Staging BUILDS the interpolated field: row (kd, hq) holds
// g_kd[n, :, d, hq, :] at pos = off(d,hq,wq)+d+kd-1. Output bf16 ch-last.
// ---------------------------------------------------------------------------
__global__ __launch_bounds__(256) void k_deform(
    const unsigned short* __restrict__ xt, const float* __restrict__ offo,
    const unsigned short* __restrict__ Bt, unsigned short* __restrict__ out1)
{
    __shared__ unsigned short A[280 * 72];
    const int h = blockIdx.x >> 1, wblk = (blockIdx.x & 1) * 28;
    const int d = blockIdx.y, n = blockIdx.z;
    const int tid = threadIdx.x;
    const int wave = tid >> 6, lane = tid & 63, lm = lane & 15, quad = lane >> 4;

    // ---- prefetch the 3 offset values this thread needs ----
    float pv[3];
#pragma unroll
    for (int it = 0; it < 3; ++it) {
        const int c = tid + it * 256;
        float p = 0.f;
        if (c < 720) {
            const int g = c / 90, rem = c - g * 90, hq3 = rem / 30, px = rem - hq3 * 30;
            const int habs = h + hq3 - 1, wq = wblk + px - 1;
            if (((unsigned)habs < 56u) & ((unsigned)wq < 56u))
                p = offo[((size_t)(n * 8 + g) * 16 + d) * HW + habs * 56 + wq] + (float)d;
        }
        pv[it] = p;
    }

    // ---- zero the 10 overrun-pad slots (read by masked MFMA rows) ----
    for (int z = tid; z < 360; z += 256) ((unsigned*)A)[9720 + z] = 0;

    // ---- gather + lerp staging: 720 tasks build all 9 (kd,hq) rows ----
#pragma unroll
    for (int it = 0; it < 3; ++it) {
        const int c = tid + it * 256;
        if (c < 720) {
            const int g = c / 90, rem = c - g * 90, hq3 = rem / 30, px = rem - hq3 * 30;
            const int habs = h + hq3 - 1, wq = wblk + px - 1;
            ushort8 o0 = (ushort8)0, o1 = (ushort8)0, o2 = (ushort8)0;
            if (((unsigned)habs < 56u) & ((unsigned)wq < 56u)) {
                const float p = pv[it];
                const float fl = floorf(p);
                const float fr = p - fl;
                const int i0 = (int)fl;
                const unsigned short* cb = xt + ((size_t)(n * 16) * HW + habs * 56 + wq) * 64 + g * 8;
                float s[4][8];
#pragma unroll
                for (int j = 0; j < 4; ++j) {
                    const int dj = i0 - 1 + j;
                    const bool ok = (unsigned)dj < 16u;
                    const ushort8 v = *(const ushort8*)(cb + (size_t)(ok ? dj : 0) * (HW * 64));
#pragma unroll
                    for (int e = 0; e < 8; ++e) s[j][e] = ok ? bf2f(v[e]) : 0.f;
                }
#pragma unroll
                for (int e = 0; e < 8; ++e) {
                    o0[e] = (unsigned short)f2bf(fmaf(fr, s[1][e] - s[0][e], s[0][e]));
                    o1[e] = (unsigned short)f2bf(fmaf(fr, s[2][e] - s[1][e], s[1][e]));
                    o2[e] = (unsigned short)f2bf(fmaf(fr, s[3][e] - s[2][e], s[2][e]));
                }
            }
            const int sl = hq3 * 30 + px;
            *(ushort8*)&A[(size_t)(sl      ) * 72 + g * 8] = o0;   // kd=0 rows 0..2
            *(ushort8*)&A[(size_t)(sl +  90) * 72 + g * 8] = o1;   // kd=1 rows 3..5
            *(ushort8*)&A[(size_t)(sl + 180) * 72 + g * 8] = o2;   // kd=2 rows 6..8
        }
    }
    __syncthreads();

    const int mf0 = wave & 1, nf0 = (wave >> 1) * 2;
    f32x4 acc[2];
    acc[0] = (f32x4){0.f, 0.f, 0.f, 0.f};
    acc[1] = (f32x4){0.f, 0.f, 0.f, 0.f};

    short8 bc[2][2];
#pragma unroll
    for (int ks = 0; ks < 2; ++ks)
#pragma unroll
        for (int nf = 0; nf < 2; ++nf)
            bc[ks][nf] = *(const short8*)(Bt + ((size_t)0 * 64 + (nf0 + nf) * 16 + lm) * 64 + ks * 32 + quad * 8);

#pragma unroll 1
    for (int t = 0; t < 27; ++t) {
        short8 bnx[2][2];
        if (t < 26) {
#pragma unroll
            for (int ks = 0; ks < 2; ++ks)
#pragma unroll
                for (int nf = 0; nf < 2; ++nf)
                    bnx[ks][nf] = *(const short8*)(Bt + ((size_t)(t + 1) * 64 + (nf0 + nf) * 16 + lm) * 64 + ks * 32 + quad * 8);
        }
        const int kd = t / 9, r9 = t - kd * 9, kh = r9 / 3, kw = r9 - kh * 3;
        const int rowb = (kd * 3 + kh) * 30 + kw;
        const unsigned short* ap = &A[(size_t)(rowb + mf0 * 16 + lm) * 72 + quad * 8];
        const short8 a0 = *(const short8*)(ap);
        const short8 a1 = *(const short8*)(ap + 32);
        acc[0] = __builtin_amdgcn_mfma_f32_16x16x32_bf16(a0, bc[0][0], acc[0], 0, 0, 0);
        acc[1] = __builtin_amdgcn_mfma_f32_16x16x32_bf16(a0, bc[0][1], acc[1], 0, 0, 0);
        acc[0] = __builtin_amdgcn_mfma_f32_16x16x32_bf16(a1, bc[1][0], acc[0], 0, 0, 0);
        acc[1] = __builtin_amdgcn_mfma_f32_16x16x32_bf16(a1, bc[1][1], acc[1], 0, 0, 0);
        if (t < 26) {
#pragma unroll
            for (int ks = 0; ks < 2; ++ks)
#pragma unroll
                for (int nf = 0; nf < 2; ++nf)
                    bc[ks][nf] = bnx[ks][nf];
        }
    }

    // ---- epilogue: bf16 tile in LDS -> coalesced ch-last stores ----
    __syncthreads();
#pragma unroll
    for (int nf = 0; nf < 2; ++nf)
#pragma unroll
        for (int r = 0; r < 4; ++r) {
            const int mm = mf0 * 16 + quad * 4 + r;
            if (mm < 28)
                A[mm * 72 + (nf0 + nf) * 16 + lm] = (unsigned short)f2bf(acc[nf][r]);
        }
    __syncthreads();
    const size_t pixb = ((size_t)(n * 16) + d) * HW + h * 56 + wblk;
    for (int c = tid; c < 224; c += 256) {
        const int px = c >> 3, kk = c & 7;
        *(uint4*)(out1 + (pixb + px) * 64 + kk * 8) = *(const uint4*)&A[px * 72 + kk * 8];
    }
}

// ---------------- per-channel stats over bf16 ch-last ----------------------
__global__ __launch_bounds__(256) void k_stats_bf16(
    const unsigned short* __restrict__ src, float* __restrict__ sums, float* __restrict__ sqs)
{
    const int c4 = threadIdx.x & 15, part = threadIdx.x >> 4;   // 16 ci-quads, 16 parts
    const size_t base = (size_t)blockIdx.x * 1024;
    float s[4] = {0.f, 0.f, 0.f, 0.f}, q[4] = {0.f, 0.f, 0.f, 0.f};
#pragma unroll 4
    for (int i = 0; i < 64; ++i) {
        const size_t pix = base + part + (size_t)i * 16;
        const uint2 v = *(const uint2*)(src + pix * 64 + c4 * 4);
        const float f0 = bf2f(v.x & 0xffffu), f1 = bf2f(v.x >> 16);
        const float f2 = bf2f(v.y & 0xffffu), f3 = bf2f(v.y >> 16);
        s[0] += f0; q[0] = fmaf(f0, f0, q[0]);
        s[1] += f1; q[1] = fmaf(f1, f1, q[1]);
        s[2] += f2; q[2] = fmaf(f2, f2, q[2]);
        s[3] += f3; q[3] = fmaf(f3, f3, q[3]);
    }
    __shared__ float S[64], Q[64];
    if (threadIdx.x < 64) { S[threadIdx.x] = 0.f; Q[threadIdx.x] = 0.f; }
    __syncthreads();
#pragma unroll
    for (int e = 0; e < 4; ++e) {
        atomicAdd(&S[c4 * 4 + e], s[e]);
        atomicAdd(&Q[c4 * 4 + e], q[e]);
    }
    __syncthreads();
    if (threadIdx.x < 64) {
        atomicAdd(&sums[threadIdx.x], S[threadIdx.x]);
        atomicAdd(&sqs[threadIdx.x],  Q[threadIdx.x]);
    }
}

// ---------------- per-channel stats, NCDHW fp32 ----------------------------
__global__ __launch_bounds__(256) void k_stats(
    const float* __restrict__ src, float* __restrict__ sums, float* __restrict__ sqs)
{
    const int c = blockIdx.x, n = blockIdx.y;
    const float* p = src + ((size_t)n * 64 + c) * DHW;
    float s = 0.f, q = 0.f;
    for (int i = threadIdx.x; i < DHW; i += 256) {
        const float v = p[i];
        s += v; q = fmaf(v, v, q);
    }
    for (int o = 32; o > 0; o >>= 1) {
        s += __shfl_down(s, o);
        q += __shfl_down(q, o);
    }
    __shared__ float ls[4], lq[4];
    const int wv = threadIdx.x >> 6, lane = threadIdx.x & 63;
    if (lane == 0) { ls[wv] = s; lq[wv] = q; }
    __syncthreads();
    if (threadIdx.x == 0) {
        atomicAdd(&sums[c], ls[0] + ls[1] + ls[2] + ls[3]);
        atomicAdd(&sqs[c],  lq[0] + lq[1] + lq[2] + lq[3]);
    }
}

// ---------------- finalize BN: scale/shift ---------------------------------
__global__ void k_finalize(const float* __restrict__ sums, const float* __restrict__ sqs,
                           const float* __restrict__ gamma, const float* __restrict__ beta,
                           float* __restrict__ scale, float* __restrict__ shift)
{
    const int c = threadIdx.x; // 64 threads
    const float mean = sums[c] / CNT;
    const float var  = sqs[c] / CNT - mean * mean;
    const float sc   = gamma[c] * rsqrtf(var + 1e-5f);
    scale[c] = sc;
    shift[c] = fmaf(-mean, sc, beta[c]);
}

// -------- BN2 + residual + ReLU: dst = relu(bn(raw) + x)  (float4) ---------
__global__ __launch_bounds__(256) void k_residual(
    float4* __restrict__ dst, const float4* __restrict__ raw,
    const float4* __restrict__ x,
    const float* __restrict__ scale, const float* __restrict__ shift)
{
    const int i = blockIdx.x * 256 + threadIdx.x;   // < 6422528
    const int c = (i / 12544) & 63;                  // wave-uniform
    const float sc = scale[c], sh = shift[c];
    float4 v = raw[i];
    const float4 xv = x[i];
    v.x = fmaxf(fmaf(v.x, sc, sh) + xv.x, 0.f);
    v.y = fmaxf(fmaf(v.y, sc, sh) + xv.y, 0.f);
    v.z = fmaxf(fmaf(v.z, sc, sh) + xv.z, 0.f);
    v.w = fmaxf(fmaf(v.w, sc, sh) + xv.w, 0.f);
    dst[i] = v;
}

extern "C" void kernel_launch(void* const* d_in, const int* in_sizes, int n_in,
                              void* d_out, int out_size, void* d_ws, size_t ws_size,
                              hipStream_t stream) {
    const float* x     = (const float*)d_in[0];
    const float* w_off = (const float*)d_in[1];
    const float* b_off = (const float*)d_in[2];
    const float* w1    = (const float*)d_in[3];
    const float* w2    = (const float*)d_in[4];
    const float* b2    = (const float*)d_in[5];
    const float* g1    = (const float*)d_in[6];
    const float* be1   = (const float*)d_in[7];
    const float* g2    = (const float*)d_in[8];
    const float* be2   = (const float*)d_in[9];

    // ---- buffer plan ----
    // d_out: [0, 2*NEL) bytes      : out1 (deform result, bf16 ch-last) -- dead after k_conv64
    //        byte 52,000,000       : weight blocks (bf16) -- dead after k_conv64
    //        [4*NEL, ...) bytes    : off output (fp32, final)
    //        [0, 4*NEL) bytes      : final out (fp32), written LAST by k_residual
    // d_ws:  [0, 2*NEL) bytes      : xt (bf16 ch-last x) -- dead after k_deform
    //        [0, 4*NEL) bytes      : raw (conv2 output fp32 NCDHW) overwrites xt
    //        [4*NEL, +2KiB)        : st stats block
    float* out     = (float*)d_out;
    float* off_out = out + NEL;
    unsigned short* out1 = (unsigned short*)d_out;
    unsigned short* wb   = (unsigned short*)(out + 13000000);  // byte 52,000,000
    unsigned short* BtO  = wb;
    unsigned short* Bt1  = BtO + 27648;
    unsigned short* Bt2  = Bt1 + 110592;

    unsigned short* xt  = (unsigned short*)d_ws;
    float*          raw = (float*)d_ws;
    float*          st  = (float*)d_ws + NEL;   // bytes [4*NEL, 4*NEL+2048)
    // st: 0 sum1 | 64 sq1 | 128 sc1 | 192 sh1 | 256 sum2 | 320 sq2 | 384 sc2 | 448 sh2

    hipMemsetAsync(st, 0, 512 * sizeof(float), stream);

    k_transpose<<<dim3(16, 8, 7), 256, 0, stream>>>(x, xt);
    k_wprep<<<432, 256, 0, stream>>>(w_off, w1, w2, BtO, Bt1, Bt2);

    const dim3 cgrid(56, 16, 8);    // h, d, n        (56-px rows, offset conv)
    const dim3 cgrid2(112, 16, 8);  // h|whalf, d, n  (28-px half rows)

    k_conv<8, false><<<cgrid, 256, 0, stream>>>(xt, BtO, b_off, nullptr, nullptr, off_out);
    k_deform<<<cgrid2, 256, 0, stream>>>(xt, off_out, Bt1, out1);

    k_stats_bf16<<<392, 256, 0, stream>>>(out1, st + 0, st + 64);
    k_finalize<<<1, 64, 0, stream>>>(st + 0, st + 64, g1, be1, st + 128, st + 192);

    k_conv64<<<cgrid2, 256, 0, stream>>>(out1, Bt2, b2, st + 128, st + 192, raw);

    k_stats<<<dim3(64, 8), 256, 0, stream>>>(raw, st + 256, st + 320);
    k_finalize<<<1, 64, 0, stream>>>(st + 256, st + 320, g2, be2, st + 384, st + 448);
    k_residual<<<25088, 256, 0, stream>>>((float4*)out, (const float4*)raw, (const float4*)x, st + 384, st + 448);
}

// Round 2
// 1511.519 us; speedup vs baseline: 1.3512x; 1.3512x over previous
//
#include <hip/hip_runtime.h>

#define HW 3136
#define DHW 50176
#define NEL 25690112   // 8*64*16*56*56
#define CNT 401408.0f  // 8*16*56*56

typedef __attribute__((ext_vector_type(8))) short          short8;
typedef __attribute__((ext_vector_type(8))) unsigned short ushort8;
typedef __attribute__((ext_vector_type(4))) float          f32x4;

__device__ __forceinline__ unsigned f2bf(float f) {
    union { float f; unsigned u; } v; v.f = f;
    return (v.u + 0x7FFFu + ((v.u >> 16) & 1u)) >> 16;   // RNE
}
__device__ __forceinline__ float bf2f(unsigned u) {
    union { unsigned u; float f; } v; v.u = u << 16;
    return v.f;
}

// ---------------------------------------------------------------------------
// x (fp32 NCDHW) -> xt (bf16, D-innermost channels-last: [n][h*w][d][ci])
// D-innermost puts the 4 lerp planes of the deform gather in ONE 512-B
// region (4 consecutive 128-B lines) instead of 4 lines 401 KB apart.
// ---------------------------------------------------------------------------
__global__ __launch_bounds__(256) void k_transpose(
    const float* __restrict__ x, unsigned short* __restrict__ xt)
{
    __shared__ unsigned lds[4][64 * 36];
    const int d = blockIdx.x, n = blockIdx.y, z = blockIdx.z;
    const int wave = threadIdx.x >> 6, lane = threadIdx.x & 63;
    const float* xb = x + (size_t)n * 64 * DHW + d * HW;
    unsigned short* xtb = xt + (size_t)n * DHW * 64;   // [hw][d][ci] inside
    unsigned* L = lds[wave];

    for (int c = z * 7 + wave; c < z * 7 + 7 && c < 49; c += 4) {
        const int P = c * 64;
#pragma unroll 4
        for (int cp = 0; cp < 32; ++cp) {
            const float a = xb[(size_t)(2 * cp) * DHW + P + lane];
            const float b = xb[(size_t)(2 * cp + 1) * DHW + P + lane];
            L[lane * 36 + cp] = f2bf(a) | (f2bf(b) << 16);
        }
#pragma unroll
        for (int k = 0; k < 8; ++k) {
            const int r = (lane >> 3) + 8 * k;          // pixel within 64-chunk
            const uint4 v = *(const uint4*)&L[r * 36 + 4 * (lane & 7)];
            *(uint4*)((char*)xtb + ((size_t)(P + r) * 16 + d) * 128 + (lane & 7) * 16) = v;
        }
    }
}

// ---------------------------------------------------------------------------
// Weight prep: BtO[27][16(8 real)][64], Bt1/Bt2[27][64][64]  (bf16)
// ---------------------------------------------------------------------------
__global__ __launch_bounds__(256) void k_wprep(
    const float* __restrict__ w_off, const float* __restrict__ w1,
    const float* __restrict__ w2, unsigned short* __restrict__ BtO,
    unsigned short* __restrict__ Bt1, unsigned short* __restrict__ Bt2)
{
    const int i = blockIdx.x * 256 + threadIdx.x;
    if (i < 27648) {
        const int t = i / 1024, r = i - t * 1024, nn = r >> 6, k = r & 63;
        BtO[i] = (nn < 8) ? (unsigned short)f2bf(w_off[(nn * 64 + k) * 27 + t]) : 0;
    }
    if (i < 110592) {
        const int t = i / 4096, r = i - t * 4096, co = r >> 6, ci = r & 63;
        Bt1[i] = (unsigned short)f2bf(w1[(co * 64 + ci) * 27 + t]);
        Bt2[i] = (unsigned short)f2bf(w2[(co * 64 + ci) * 27 + t]);
    }
}

// ---------------------------------------------------------------------------
// Standard 3x3x3 conv via MFMA, LDS-staged. Block = (h, d, n), 256 thr.
// A-tile: 9 rows (3 dq x 3 hq) x 58 px x 64 ci bf16, row stride 72 shorts.
// DIN: input is D-innermost ([n][hw][d][ci], the xt layout); else D-major
// pixel-major ch-last ([n*16+d][hw][ci], the out1 layout).
// ---------------------------------------------------------------------------
template<int NCO, bool BN, bool DIN>
__global__ __launch_bounds__(256) void k_conv(
    const unsigned short* __restrict__ src, const unsigned short* __restrict__ Bt,
    const float* __restrict__ bias, const float* __restrict__ scv,
    const float* __restrict__ shv, float* __restrict__ dst)
{
    __shared__ unsigned short A[538 * 72];   // 9*58=522 slots + 16 overrun pad
    const int h = blockIdx.x, d = blockIdx.y, n = blockIdx.z;
    const int tid = threadIdx.x;
    const int wave = tid >> 6, lane = tid & 63, lm = lane & 15, quad = lane >> 4;
    const int k8 = tid & 7;                  // fixed ci-chunk per thread

    float scr[8], shr[8];
    if constexpr (BN) {
#pragma unroll
        for (int e = 0; e < 8; ++e) { scr[e] = scv[k8 * 8 + e]; shr[e] = shv[k8 * 8 + e]; }
    }

    const unsigned short* snb = DIN ? (src + (size_t)n * DHW * 64)
                                    : (src + (size_t)(n * 16) * HW * 64);

    // ---- stage 4176 16B chunks ----
    for (int c = tid; c < 4176; c += 256) {
        const int idx = c >> 3;
        const int row = idx / 58, px = idx - row * 58;
        const int kd = row / 3, kh = row - kd * 3;
        const int dq = d + kd - 1, hq = h + kh - 1, wq = px - 1;
        ushort8 val = (ushort8)0;
        if (((unsigned)dq < 16u) & ((unsigned)hq < 56u) & ((unsigned)wq < 56u)) {
            const size_t off = DIN ? (((size_t)(hq * 56 + wq) * 16 + dq) * 64)
                                   : (((size_t)dq * HW + hq * 56 + wq) * 64);
            val = *(const ushort8*)(snb + off + k8 * 8);
            if constexpr (BN) {
#pragma unroll
                for (int e = 0; e < 8; ++e) {
                    const float f = fmaxf(fmaf(bf2f(val[e]), scr[e], shr[e]), 0.f);
                    val[e] = (unsigned short)f2bf(f);
                }
            }
        }
        *(ushort8*)&A[(size_t)idx * 72 + k8 * 8] = val;
    }
    __syncthreads();

    constexpr int NB  = (NCO == 8) ? 16 : 64;
    constexpr int NFm = (NCO == 8) ? 1 : 2;
    constexpr int NFn = (NCO == 8) ? 1 : 2;
    const int mf0 = (NCO == 8) ? wave : (wave & 1) * 2;
    const int nf0 = (NCO == 8) ? 0 : (wave >> 1) * 2;

    f32x4 acc[NFm][NFn];
#pragma unroll
    for (int i = 0; i < NFm; ++i)
#pragma unroll
        for (int j = 0; j < NFn; ++j) acc[i][j] = (f32x4){0.f, 0.f, 0.f, 0.f};

    // ---- 27-tap K-loop, B software-pipelined ----
    short8 bc[2][NFn];
#pragma unroll
    for (int ks = 0; ks < 2; ++ks)
#pragma unroll
        for (int nf = 0; nf < NFn; ++nf)
            bc[ks][nf] = *(const short8*)(Bt + ((size_t)0 * NB + (nf0 + nf) * 16 + lm) * 64 + ks * 32 + quad * 8);

#pragma unroll 1
    for (int t = 0; t < 27; ++t) {
        short8 bnx[2][NFn];
        if (t < 26) {
#pragma unroll
            for (int ks = 0; ks < 2; ++ks)
#pragma unroll
                for (int nf = 0; nf < NFn; ++nf)
                    bnx[ks][nf] = *(const short8*)(Bt + ((size_t)(t + 1) * NB + (nf0 + nf) * 16 + lm) * 64 + ks * 32 + quad * 8);
        }
        const int kd = t / 9, r9 = t - kd * 9, kh = r9 / 3, kw = r9 - kh * 3;
        const int rowb = (kd * 3 + kh) * 58 + kw;
        short8 a[2][NFm];
#pragma unroll
        for (int ks = 0; ks < 2; ++ks)
#pragma unroll
            for (int mf = 0; mf < NFm; ++mf)
                a[ks][mf] = *(const short8*)&A[(size_t)(rowb + (mf0 + mf) * 16 + lm) * 72 + ks * 32 + quad * 8];
#pragma unroll
        for (int ks = 0; ks < 2; ++ks)
#pragma unroll
            for (int mf = 0; mf < NFm; ++mf)
#pragma unroll
                for (int nf = 0; nf < NFn; ++nf)
                    acc[mf][nf] = __builtin_amdgcn_mfma_f32_16x16x32_bf16(a[ks][mf], bc[ks][nf], acc[mf][nf], 0, 0, 0);
        if (t < 26) {
#pragma unroll
            for (int ks = 0; ks < 2; ++ks)
#pragma unroll
                for (int nf = 0; nf < NFn; ++nf)
                    bc[ks][nf] = bnx[ks][nf];
        }
    }

    // ---- epilogue: LDS transpose -> fp32 NCDHW + bias ----
    __syncthreads();
    float* E = (float*)A;
    constexpr int CSTR = (NCO == 64) ? 65 : 17;
#pragma unroll
    for (int mf = 0; mf < NFm; ++mf)
#pragma unroll
        for (int nf = 0; nf < NFn; ++nf)
#pragma unroll
            for (int r = 0; r < 4; ++r) {
                const int mm = (mf0 + mf) * 16 + quad * 4 + r;
                if (mm < 56) E[mm * CSTR + (nf0 + nf) * 16 + lm] = acc[mf][nf][r];
            }
    __syncthreads();
    for (int f = tid; f < 56 * NCO; f += 256) {
        const int co = f / 56, w0 = f - co * 56;
        dst[((size_t)(n * NCO + co) * 16 + d) * HW + h * 56 + w0] = E[w0 * CSTR + co] + bias[co];
    }
}

// ---------------------------------------------------------------------------
// Temporal deformable conv. Staging BUILDS the interpolated field: row
// (kd, hq) holds g_kd[n, :, d, hq, :] at pos = off(d,hq,wq)+d+kd-1.
// xt is D-innermost: the 4 lerp planes are 4 consecutive 128-B lines.
// Output: bf16 ch-last [pixel][co] (D-major, feeds k_conv<64>).
// ---------------------------------------------------------------------------
__global__ __launch_bounds__(256) void k_deform(
    const unsigned short* __restrict__ xt, const float* __restrict__ offo,
    const unsigned short* __restrict__ Bt, unsigned short* __restrict__ out1)
{
    __shared__ unsigned short A[538 * 72];
    const int h = blockIdx.x, d = blockIdx.y, n = blockIdx.z;
    const int tid = threadIdx.x;
    const int wave = tid >> 6, lane = tid & 63, lm = lane & 15, quad = lane >> 4;

    // ---- prefetch the 6 offset values this thread needs ----
    float pv[6];
#pragma unroll
    for (int it = 0; it < 6; ++it) {
        const int c = tid + it * 256;
        float p = 0.f;
        if (c < 1392) {
            const int g = c / 174, rem = c - g * 174, hq3 = rem / 58, px = rem - hq3 * 58;
            const int habs = h + hq3 - 1, wq = px - 1;
            if (((unsigned)habs < 56u) & ((unsigned)wq < 56u))
                p = offo[((size_t)(n * 8 + g) * 16 + d) * HW + habs * 56 + wq] + (float)d;
        }
        pv[it] = p;
    }

    // ---- gather + lerp staging: 1392 tasks build all 9 (kd,hq) rows ----
#pragma unroll 2
    for (int it = 0; it < 6; ++it) {
        const int c = tid + it * 256;
        if (c >= 1392) break;
        const int g = c / 174, rem = c - g * 174, hq3 = rem / 58, px = rem - hq3 * 58;
        const int habs = h + hq3 - 1, wq = px - 1;
        ushort8 o0 = (ushort8)0, o1 = (ushort8)0, o2 = (ushort8)0;
        if (((unsigned)habs < 56u) & ((unsigned)wq < 56u)) {
            const float p = pv[it];
            const float fl = floorf(p);
            const float fr = p - fl;
            const int i0 = (int)fl;
            // D-innermost: plane stride is 64 shorts (128 B)
            const unsigned short* cb = xt + ((size_t)n * HW + habs * 56 + wq) * (16 * 64) + g * 8;
            float s[4][8];
#pragma unroll
            for (int j = 0; j < 4; ++j) {
                const int dj = i0 - 1 + j;
                const bool ok = (unsigned)dj < 16u;
                const ushort8 v = *(const ushort8*)(cb + (size_t)(ok ? dj : 0) * 64);
#pragma unroll
                for (int e = 0; e < 8; ++e) s[j][e] = ok ? bf2f(v[e]) : 0.f;
            }
#pragma unroll
            for (int e = 0; e < 8; ++e) {
                o0[e] = (unsigned short)f2bf(fmaf(fr, s[1][e] - s[0][e], s[0][e]));
                o1[e] = (unsigned short)f2bf(fmaf(fr, s[2][e] - s[1][e], s[1][e]));
                o2[e] = (unsigned short)f2bf(fmaf(fr, s[3][e] - s[2][e], s[2][e]));
            }
        }
        const int sl = hq3 * 58 + px;
        *(ushort8*)&A[(size_t)(sl          ) * 72 + g * 8] = o0;   // kd=0 rows 0..2
        *(ushort8*)&A[(size_t)(sl + 3 * 58 ) * 72 + g * 8] = o1;   // kd=1 rows 3..5
        *(ushort8*)&A[(size_t)(sl + 6 * 58 ) * 72 + g * 8] = o2;   // kd=2 rows 6..8
    }
    __syncthreads();

    const int mf0 = (wave & 1) * 2, nf0 = (wave >> 1) * 2;
    f32x4 acc[2][2];
#pragma unroll
    for (int i = 0; i < 2; ++i)
#pragma unroll
        for (int j = 0; j < 2; ++j) acc[i][j] = (f32x4){0.f, 0.f, 0.f, 0.f};

    short8 bc[2][2];
#pragma unroll
    for (int ks = 0; ks < 2; ++ks)
#pragma unroll
        for (int nf = 0; nf < 2; ++nf)
            bc[ks][nf] = *(const short8*)(Bt + ((size_t)0 * 64 + (nf0 + nf) * 16 + lm) * 64 + ks * 32 + quad * 8);

#pragma unroll 1
    for (int t = 0; t < 27; ++t) {
        short8 bnx[2][2];
        if (t < 26) {
#pragma unroll
            for (int ks = 0; ks < 2; ++ks)
#pragma unroll
                for (int nf = 0; nf < 2; ++nf)
                    bnx[ks][nf] = *(const short8*)(Bt + ((size_t)(t + 1) * 64 + (nf0 + nf) * 16 + lm) * 64 + ks * 32 + quad * 8);
        }
        const int kd = t / 9, r9 = t - kd * 9, kh = r9 / 3, kw = r9 - kh * 3;
        const int rowb = (kd * 3 + kh) * 58 + kw;
        short8 a[2][2];
#pragma unroll
        for (int ks = 0; ks < 2; ++ks)
#pragma unroll
            for (int mf = 0; mf < 2; ++mf)
                a[ks][mf] = *(const short8*)&A[(size_t)(rowb + (mf0 + mf) * 16 + lm) * 72 + ks * 32 + quad * 8];
#pragma unroll
        for (int ks = 0; ks < 2; ++ks)
#pragma unroll
            for (int mf = 0; mf < 2; ++mf)
#pragma unroll
                for (int nf = 0; nf < 2; ++nf)
                    acc[mf][nf] = __builtin_amdgcn_mfma_f32_16x16x32_bf16(a[ks][mf], bc[ks][nf], acc[mf][nf], 0, 0, 0);
        if (t < 26) {
#pragma unroll
            for (int ks = 0; ks < 2; ++ks)
#pragma unroll
                for (int nf = 0; nf < 2; ++nf)
                    bc[ks][nf] = bnx[ks][nf];
        }
    }

    // ---- epilogue: bf16 tile in LDS -> coalesced ch-last stores ----
    __syncthreads();
#pragma unroll
    for (int mf = 0; mf < 2; ++mf)
#pragma unroll
        for (int nf = 0; nf < 2; ++nf)
#pragma unroll
            for (int r = 0; r < 4; ++r) {
                const int mm = (mf0 + mf) * 16 + quad * 4 + r;
                if (mm < 56)
                    A[mm * 72 + (nf0 + nf) * 16 + lm] = (unsigned short)f2bf(acc[mf][nf][r]);
            }
    __syncthreads();
    const size_t pixb = ((size_t)(n * 16) + d) * HW + h * 56;
    for (int c = tid; c < 448; c += 256) {
        const int px = c >> 3, kk = c & 7;
        *(uint4*)(out1 + (pixb + px) * 64 + kk * 8) = *(const uint4*)&A[px * 72 + kk * 8];
    }
}

// ---------------- per-channel stats over bf16 ch-last ----------------------
__global__ __launch_bounds__(256) void k_stats_bf16(
    const unsigned short* __restrict__ src, float* __restrict__ sums, float* __restrict__ sqs)
{
    const int c4 = threadIdx.x & 15, part = threadIdx.x >> 4;   // 16 ci-quads, 16 parts
    const size_t base = (size_t)blockIdx.x * 1024;
    float s[4] = {0.f, 0.f, 0.f, 0.f}, q[4] = {0.f, 0.f, 0.f, 0.f};
#pragma unroll 4
    for (int i = 0; i < 64; ++i) {
        const size_t pix = base + part + (size_t)i * 16;
        const uint2 v = *(const uint2*)(src + pix * 64 + c4 * 4);
        const float f0 = bf2f(v.x & 0xffffu), f1 = bf2f(v.x >> 16);
        const float f2 = bf2f(v.y & 0xffffu), f3 = bf2f(v.y >> 16);
        s[0] += f0; q[0] = fmaf(f0, f0, q[0]);
        s[1] += f1; q[1] = fmaf(f1, f1, q[1]);
        s[2] += f2; q[2] = fmaf(f2, f2, q[2]);
        s[3] += f3; q[3] = fmaf(f3, f3, q[3]);
    }
    __shared__ float S[64], Q[64];
    if (threadIdx.x < 64) { S[threadIdx.x] = 0.f; Q[threadIdx.x] = 0.f; }
    __syncthreads();
#pragma unroll
    for (int e = 0; e < 4; ++e) {
        atomicAdd(&S[c4 * 4 + e], s[e]);
        atomicAdd(&Q[c4 * 4 + e], q[e]);
    }
    __syncthreads();
    if (threadIdx.x < 64) {
        atomicAdd(&sums[threadIdx.x], S[threadIdx.x]);
        atomicAdd(&sqs[threadIdx.x],  Q[threadIdx.x]);
    }
}

// ---------------- per-channel stats, NCDHW fp32 ----------------------------
__global__ __launch_bounds__(256) void k_stats(
    const float* __restrict__ src, float* __restrict__ sums, float* __restrict__ sqs)
{
    const int c = blockIdx.x, n = blockIdx.y;
    const float* p = src + ((size_t)n * 64 + c) * DHW;
    float s = 0.f, q = 0.f;
    for (int i = threadIdx.x; i < DHW; i += 256) {
        const float v = p[i];
        s += v; q = fmaf(v, v, q);
    }
    for (int o = 32; o > 0; o >>= 1) {
        s += __shfl_down(s, o);
        q += __shfl_down(q, o);
    }
    __shared__ float ls[4], lq[4];
    const int wv = threadIdx.x >> 6, lane = threadIdx.x & 63;
    if (lane == 0) { ls[wv] = s; lq[wv] = q; }
    __syncthreads();
    if (threadIdx.x == 0) {
        atomicAdd(&sums[c], ls[0] + ls[1] + ls[2] + ls[3]);
        atomicAdd(&sqs[c],  lq[0] + lq[1] + lq[2] + lq[3]);
    }
}

// ---------------- finalize BN: scale/shift ---------------------------------
__global__ void k_finalize(const float* __restrict__ sums, const float* __restrict__ sqs,
                           const float* __restrict__ gamma, const float* __restrict__ beta,
                           float* __restrict__ scale, float* __restrict__ shift)
{
    const int c = threadIdx.x; // 64 threads
    const float mean = sums[c] / CNT;
    const float var  = sqs[c] / CNT - mean * mean;
    const float sc   = gamma[c] * rsqrtf(var + 1e-5f);
    scale[c] = sc;
    shift[c] = fmaf(-mean, sc, beta[c]);
}

// -------- BN2 + residual + ReLU: dst = relu(bn(raw) + x)  (float4) ---------
__global__ __launch_bounds__(256) void k_residual(
    float4* __restrict__ dst, const float4* __restrict__ raw,
    const float4* __restrict__ x,
    const float* __restrict__ scale, const float* __restrict__ shift)
{
    const int i = blockIdx.x * 256 + threadIdx.x;   // < 6422528
    const int c = (i / 12544) & 63;                  // wave-uniform
    const float sc = scale[c], sh = shift[c];
    float4 v = raw[i];
    const float4 xv = x[i];
    v.x = fmaxf(fmaf(v.x, sc, sh) + xv.x, 0.f);
    v.y = fmaxf(fmaf(v.y, sc, sh) + xv.y, 0.f);
    v.z = fmaxf(fmaf(v.z, sc, sh) + xv.z, 0.f);
    v.w = fmaxf(fmaf(v.w, sc, sh) + xv.w, 0.f);
    dst[i] = v;
}

extern "C" void kernel_launch(void* const* d_in, const int* in_sizes, int n_in,
                              void* d_out, int out_size, void* d_ws, size_t ws_size,
                              hipStream_t stream) {
    const float* x     = (const float*)d_in[0];
    const float* w_off = (const float*)d_in[1];
    const float* b_off = (const float*)d_in[2];
    const float* w1    = (const float*)d_in[3];
    const float* w2    = (const float*)d_in[4];
    const float* b2    = (const float*)d_in[5];
    const float* g1    = (const float*)d_in[6];
    const float* be1   = (const float*)d_in[7];
    const float* g2    = (const float*)d_in[8];
    const float* be2   = (const float*)d_in[9];

    // ---- buffer plan ----
    // d_out: [0, 2*NEL) bytes      : out1 (deform result, bf16 ch-last) -- dead after k_conv<64>
    //        byte 52,000,000       : weight blocks (bf16) -- dead after k_conv<64>
    //        [4*NEL, ...) bytes    : off output (fp32, final)
    //        [0, 4*NEL) bytes      : final out (fp32), written LAST by k_residual
    // d_ws:  [0, 2*NEL) bytes      : xt (bf16 D-innermost x) -- dead after k_deform
    //        [0, 4*NEL) bytes      : raw (conv2 output fp32 NCDHW) overwrites xt
    //        [4*NEL, +2KiB)        : st stats block
    float* out     = (float*)d_out;
    float* off_out = out + NEL;
    unsigned short* out1 = (unsigned short*)d_out;
    unsigned short* wb   = (unsigned short*)(out + 13000000);  // byte 52,000,000
    unsigned short* BtO  = wb;
    unsigned short* Bt1  = BtO + 27648;
    unsigned short* Bt2  = Bt1 + 110592;

    unsigned short* xt  = (unsigned short*)d_ws;
    float*          raw = (float*)d_ws;
    float*          st  = (float*)d_ws + NEL;   // bytes [4*NEL, 4*NEL+2048)
    // st: 0 sum1 | 64 sq1 | 128 sc1 | 192 sh1 | 256 sum2 | 320 sq2 | 384 sc2 | 448 sh2

    hipMemsetAsync(st, 0, 512 * sizeof(float), stream);

    k_transpose<<<dim3(16, 8, 7), 256, 0, stream>>>(x, xt);
    k_wprep<<<432, 256, 0, stream>>>(w_off, w1, w2, BtO, Bt1, Bt2);

    const dim3 cgrid(56, 16, 8);   // h, d, n
    k_conv<8, false, true><<<cgrid, 256, 0, stream>>>(xt, BtO, b_off, nullptr, nullptr, off_out);
    k_deform<<<cgrid, 256, 0, stream>>>(xt, off_out, Bt1, out1);

    k_stats_bf16<<<392, 256, 0, stream>>>(out1, st + 0, st + 64);
    k_finalize<<<1, 64, 0, stream>>>(st + 0, st + 64, g1, be1, st + 128, st + 192);

    k_conv<64, true, false><<<cgrid, 256, 0, stream>>>(out1, Bt2, b2, st + 128, st + 192, raw);

    k_stats<<<dim3(64, 8), 256, 0, stream>>>(raw, st + 256, st + 320);
    k_finalize<<<1, 64, 0, stream>>>(st + 256, st + 320, g2, be2, st + 384, st + 448);
    k_residual<<<25088, 256, 0, stream>>>((float4*)out, (const float4*)raw, (const float4*)x, st + 384, st + 448);
}

// Round 3
// 1444.734 us; speedup vs baseline: 1.4137x; 1.0462x over previous
//
#include <hip/hip_runtime.h>

#define HW 3136
#define DHW 50176
#define NEL 25690112   // 8*64*16*56*56
#define CNT 401408.0f  // 8*16*56*56

typedef __attribute__((ext_vector_type(8))) short          short8;
typedef __attribute__((ext_vector_type(8))) unsigned short ushort8;
typedef __attribute__((ext_vector_type(4))) float          f32x4;

__device__ __forceinline__ unsigned f2bf(float f) {
    union { float f; unsigned u; } v; v.f = f;
    return (v.u + 0x7FFFu + ((v.u >> 16) & 1u)) >> 16;   // RNE
}
__device__ __forceinline__ float bf2f(unsigned u) {
    union { unsigned u; float f; } v; v.u = u << 16;
    return v.f;
}

// XCD-aware swizzle for the 56x16x8 grids: linear bid -> logical id such
// that XCD k (= bid % 8 under round-robin dispatch) executes the contiguous
// logical range [k*896, (k+1)*896) = ALL (h,d) of batch n=k. Each XCD's
// 4 MB L2 then serves one n's xt/out1 slice; adjacent-h blocks (2/3 A-tile
// overlap) hit in L2 instead of re-missing to HBM.
__device__ __forceinline__ void xcd_decode(int& h, int& d, int& n) {
    const int bid = blockIdx.x + 56 * (blockIdx.y + 16 * blockIdx.z);
    const int swz = (bid & 7) * 896 + (bid >> 3);
    h = swz % 56;
    const int dn = swz / 56;   // dn = d + 16*n, < 128
    d = dn & 15;
    n = dn >> 4;
}

// ---------------------------------------------------------------------------
// x (fp32 NCDHW) -> xt (bf16, D-innermost channels-last: [n][h*w][d][ci])
// ---------------------------------------------------------------------------
__global__ __launch_bounds__(256) void k_transpose(
    const float* __restrict__ x, unsigned short* __restrict__ xt)
{
    __shared__ unsigned lds[4][64 * 36];
    const int d = blockIdx.x, n = blockIdx.y, z = blockIdx.z;
    const int wave = threadIdx.x >> 6, lane = threadIdx.x & 63;
    const float* xb = x + (size_t)n * 64 * DHW + d * HW;
    unsigned short* xtb = xt + (size_t)n * DHW * 64;   // [hw][d][ci] inside
    unsigned* L = lds[wave];

    for (int c = z * 7 + wave; c < z * 7 + 7 && c < 49; c += 4) {
        const int P = c * 64;
#pragma unroll 4
        for (int cp = 0; cp < 32; ++cp) {
            const float a = xb[(size_t)(2 * cp) * DHW + P + lane];
            const float b = xb[(size_t)(2 * cp + 1) * DHW + P + lane];
            L[lane * 36 + cp] = f2bf(a) | (f2bf(b) << 16);
        }
#pragma unroll
        for (int k = 0; k < 8; ++k) {
            const int r = (lane >> 3) + 8 * k;          // pixel within 64-chunk
            const uint4 v = *(const uint4*)&L[r * 36 + 4 * (lane & 7)];
            *(uint4*)((char*)xtb + ((size_t)(P + r) * 16 + d) * 128 + (lane & 7) * 16) = v;
        }
    }
}

// ---------------------------------------------------------------------------
// Weight prep: BtO[27][16(8 real)][64], Bt1/Bt2[27][64][64]  (bf16)
// ---------------------------------------------------------------------------
__global__ __launch_bounds__(256) void k_wprep(
    const float* __restrict__ w_off, const float* __restrict__ w1,
    const float* __restrict__ w2, unsigned short* __restrict__ BtO,
    unsigned short* __restrict__ Bt1, unsigned short* __restrict__ Bt2)
{
    const int i = blockIdx.x * 256 + threadIdx.x;
    if (i < 27648) {
        const int t = i / 1024, r = i - t * 1024, nn = r >> 6, k = r & 63;
        BtO[i] = (nn < 8) ? (unsigned short)f2bf(w_off[(nn * 64 + k) * 27 + t]) : 0;
    }
    if (i < 110592) {
        const int t = i / 4096, r = i - t * 4096, co = r >> 6, ci = r & 63;
        Bt1[i] = (unsigned short)f2bf(w1[(co * 64 + ci) * 27 + t]);
        Bt2[i] = (unsigned short)f2bf(w2[(co * 64 + ci) * 27 + t]);
    }
}

// ---------------------------------------------------------------------------
// Standard 3x3x3 conv via MFMA, LDS-staged. Block = (h, d, n), 256 thr.
// A-tile: 9 rows (3 dq x 3 hq) x 58 px x 64 ci bf16, row stride 72 shorts.
// DIN: input is D-innermost ([n][hw][d][ci], the xt layout); else D-major
// pixel-major ch-last ([n*16+d][hw][ci], the out1 layout).
// ---------------------------------------------------------------------------
template<int NCO, bool BN, bool DIN>
__global__ __launch_bounds__(256) void k_conv(
    const unsigned short* __restrict__ src, const unsigned short* __restrict__ Bt,
    const float* __restrict__ bias, const float* __restrict__ scv,
    const float* __restrict__ shv, float* __restrict__ dst)
{
    __shared__ unsigned short A[538 * 72];   // 9*58=522 slots + 16 overrun pad
    int h, d, n;
    xcd_decode(h, d, n);
    const int tid = threadIdx.x;
    const int wave = tid >> 6, lane = tid & 63, lm = lane & 15, quad = lane >> 4;
    const int k8 = tid & 7;                  // fixed ci-chunk per thread

    float scr[8], shr[8];
    if constexpr (BN) {
#pragma unroll
        for (int e = 0; e < 8; ++e) { scr[e] = scv[k8 * 8 + e]; shr[e] = shv[k8 * 8 + e]; }
    }

    const unsigned short* snb = DIN ? (src + (size_t)n * DHW * 64)
                                    : (src + (size_t)(n * 16) * HW * 64);

    // ---- stage 4176 16B chunks ----
    for (int c = tid; c < 4176; c += 256) {
        const int idx = c >> 3;
        const int row = idx / 58, px = idx - row * 58;
        const int kd = row / 3, kh = row - kd * 3;
        const int dq = d + kd - 1, hq = h + kh - 1, wq = px - 1;
        ushort8 val = (ushort8)0;
        if (((unsigned)dq < 16u) & ((unsigned)hq < 56u) & ((unsigned)wq < 56u)) {
            const size_t off = DIN ? (((size_t)(hq * 56 + wq) * 16 + dq) * 64)
                                   : (((size_t)dq * HW + hq * 56 + wq) * 64);
            val = *(const ushort8*)(snb + off + k8 * 8);
            if constexpr (BN) {
#pragma unroll
                for (int e = 0; e < 8; ++e) {
                    const float f = fmaxf(fmaf(bf2f(val[e]), scr[e], shr[e]), 0.f);
                    val[e] = (unsigned short)f2bf(f);
                }
            }
        }
        *(ushort8*)&A[(size_t)idx * 72 + k8 * 8] = val;
    }
    __syncthreads();

    constexpr int NB  = (NCO == 8) ? 16 : 64;
    constexpr int NFm = (NCO == 8) ? 1 : 2;
    constexpr int NFn = (NCO == 8) ? 1 : 2;
    const int mf0 = (NCO == 8) ? wave : (wave & 1) * 2;
    const int nf0 = (NCO == 8) ? 0 : (wave >> 1) * 2;

    f32x4 acc[NFm][NFn];
#pragma unroll
    for (int i = 0; i < NFm; ++i)
#pragma unroll
        for (int j = 0; j < NFn; ++j) acc[i][j] = (f32x4){0.f, 0.f, 0.f, 0.f};

    // ---- 27-tap K-loop, B software-pipelined ----
    short8 bc[2][NFn];
#pragma unroll
    for (int ks = 0; ks < 2; ++ks)
#pragma unroll
        for (int nf = 0; nf < NFn; ++nf)
            bc[ks][nf] = *(const short8*)(Bt + ((size_t)0 * NB + (nf0 + nf) * 16 + lm) * 64 + ks * 32 + quad * 8);

#pragma unroll 1
    for (int t = 0; t < 27; ++t) {
        short8 bnx[2][NFn];
        if (t < 26) {
#pragma unroll
            for (int ks = 0; ks < 2; ++ks)
#pragma unroll
                for (int nf = 0; nf < NFn; ++nf)
                    bnx[ks][nf] = *(const short8*)(Bt + ((size_t)(t + 1) * NB + (nf0 + nf) * 16 + lm) * 64 + ks * 32 + quad * 8);
        }
        const int kd = t / 9, r9 = t - kd * 9, kh = r9 / 3, kw = r9 - kh * 3;
        const int rowb = (kd * 3 + kh) * 58 + kw;
        short8 a[2][NFm];
#pragma unroll
        for (int ks = 0; ks < 2; ++ks)
#pragma unroll
            for (int mf = 0; mf < NFm; ++mf)
                a[ks][mf] = *(const short8*)&A[(size_t)(rowb + (mf0 + mf) * 16 + lm) * 72 + ks * 32 + quad * 8];
#pragma unroll
        for (int ks = 0; ks < 2; ++ks)
#pragma unroll
            for (int mf = 0; mf < NFm; ++mf)
#pragma unroll
                for (int nf = 0; nf < NFn; ++nf)
                    acc[mf][nf] = __builtin_amdgcn_mfma_f32_16x16x32_bf16(a[ks][mf], bc[ks][nf], acc[mf][nf], 0, 0, 0);
        if (t < 26) {
#pragma unroll
            for (int ks = 0; ks < 2; ++ks)
#pragma unroll
                for (int nf = 0; nf < NFn; ++nf)
                    bc[ks][nf] = bnx[ks][nf];
        }
    }

    // ---- epilogue: LDS transpose -> fp32 NCDHW + bias ----
    __syncthreads();
    float* E = (float*)A;
    constexpr int CSTR = (NCO == 64) ? 65 : 17;
#pragma unroll
    for (int mf = 0; mf < NFm; ++mf)
#pragma unroll
        for (int nf = 0; nf < NFn; ++nf)
#pragma unroll
            for (int r = 0; r < 4; ++r) {
                const int mm = (mf0 + mf) * 16 + quad * 4 + r;
                if (mm < 56) E[mm * CSTR + (nf0 + nf) * 16 + lm] = acc[mf][nf][r];
            }
    __syncthreads();
    for (int f = tid; f < 56 * NCO; f += 256) {
        const int co = f / 56, w0 = f - co * 56;
        dst[((size_t)(n * NCO + co) * 16 + d) * HW + h * 56 + w0] = E[w0 * CSTR + co] + bias[co];
    }
}

// ---------------------------------------------------------------------------
// Temporal deformable conv. Staging BUILDS the interpolated field: row
// (kd, hq) holds g_kd[n, :, d, hq, :] at pos = off(d,hq,wq)+d+kd-1.
// xt is D-innermost: the 4 lerp planes are 4 consecutive 128-B lines.
// Output: bf16 ch-last [pixel][co] (D-major, feeds k_conv<64>).
// ---------------------------------------------------------------------------
__global__ __launch_bounds__(256) void k_deform(
    const unsigned short* __restrict__ xt, const float* __restrict__ offo,
    const unsigned short* __restrict__ Bt, unsigned short* __restrict__ out1)
{
    __shared__ unsigned short A[538 * 72];
    int h, d, n;
    xcd_decode(h, d, n);
    const int tid = threadIdx.x;
    const int wave = tid >> 6, lane = tid & 63, lm = lane & 15, quad = lane >> 4;

    // ---- prefetch the 6 offset values this thread needs ----
    float pv[6];
#pragma unroll
    for (int it = 0; it < 6; ++it) {
        const int c = tid + it * 256;
        float p = 0.f;
        if (c < 1392) {
            const int g = c / 174, rem = c - g * 174, hq3 = rem / 58, px = rem - hq3 * 58;
            const int habs = h + hq3 - 1, wq = px - 1;
            if (((unsigned)habs < 56u) & ((unsigned)wq < 56u))
                p = offo[((size_t)(n * 8 + g) * 16 + d) * HW + habs * 56 + wq] + (float)d;
        }
        pv[it] = p;
    }

    // ---- gather + lerp staging: 1392 tasks build all 9 (kd,hq) rows ----
#pragma unroll 2
    for (int it = 0; it < 6; ++it) {
        const int c = tid + it * 256;
        if (c >= 1392) break;
        const int g = c / 174, rem = c - g * 174, hq3 = rem / 58, px = rem - hq3 * 58;
        const int habs = h + hq3 - 1, wq = px - 1;
        ushort8 o0 = (ushort8)0, o1 = (ushort8)0, o2 = (ushort8)0;
        if (((unsigned)habs < 56u) & ((unsigned)wq < 56u)) {
            const float p = pv[it];
            const float fl = floorf(p);
            const float fr = p - fl;
            const int i0 = (int)fl;
            // D-innermost: plane stride is 64 shorts (128 B)
            const unsigned short* cb = xt + ((size_t)n * HW + habs * 56 + wq) * (16 * 64) + g * 8;
            float s[4][8];
#pragma unroll
            for (int j = 0; j < 4; ++j) {
                const int dj = i0 - 1 + j;
                const bool ok = (unsigned)dj < 16u;
                const ushort8 v = *(const ushort8*)(cb + (size_t)(ok ? dj : 0) * 64);
#pragma unroll
                for (int e = 0; e < 8; ++e) s[j][e] = ok ? bf2f(v[e]) : 0.f;
            }
#pragma unroll
            for (int e = 0; e < 8; ++e) {
                o0[e] = (unsigned short)f2bf(fmaf(fr, s[1][e] - s[0][e], s[0][e]));
                o1[e] = (unsigned short)f2bf(fmaf(fr, s[2][e] - s[1][e], s[1][e]));
                o2[e] = (unsigned short)f2bf(fmaf(fr, s[3][e] - s[2][e], s[2][e]));
            }
        }
        const int sl = hq3 * 58 + px;
        *(ushort8*)&A[(size_t)(sl          ) * 72 + g * 8] = o0;   // kd=0 rows 0..2
        *(ushort8*)&A[(size_t)(sl + 3 * 58 ) * 72 + g * 8] = o1;   // kd=1 rows 3..5
        *(ushort8*)&A[(size_t)(sl + 6 * 58 ) * 72 + g * 8] = o2;   // kd=2 rows 6..8
    }
    __syncthreads();

    const int mf0 = (wave & 1) * 2, nf0 = (wave >> 1) * 2;
    f32x4 acc[2][2];
#pragma unroll
    for (int i = 0; i < 2; ++i)
#pragma unroll
        for (int j = 0; j < 2; ++j) acc[i][j] = (f32x4){0.f, 0.f, 0.f, 0.f};

    short8 bc[2][2];
#pragma unroll
    for (int ks = 0; ks < 2; ++ks)
#pragma unroll
        for (int nf = 0; nf < 2; ++nf)
            bc[ks][nf] = *(const short8*)(Bt + ((size_t)0 * 64 + (nf0 + nf) * 16 + lm) * 64 + ks * 32 + quad * 8);

#pragma unroll 1
    for (int t = 0; t < 27; ++t) {
        short8 bnx[2][2];
        if (t < 26) {
#pragma unroll
            for (int ks = 0; ks < 2; ++ks)
#pragma unroll
                for (int nf = 0; nf < 2; ++nf)
                    bnx[ks][nf] = *(const short8*)(Bt + ((size_t)(t + 1) * 64 + (nf0 + nf) * 16 + lm) * 64 + ks * 32 + quad * 8);
        }
        const int kd = t / 9, r9 = t - kd * 9, kh = r9 / 3, kw = r9 - kh * 3;
        const int rowb = (kd * 3 + kh) * 58 + kw;
        short8 a[2][2];
#pragma unroll
        for (int ks = 0; ks < 2; ++ks)
#pragma unroll
            for (int mf = 0; mf < 2; ++mf)
                a[ks][mf] = *(const short8*)&A[(size_t)(rowb + (mf0 + mf) * 16 + lm) * 72 + ks * 32 + quad * 8];
#pragma unroll
        for (int ks = 0; ks < 2; ++ks)
#pragma unroll
            for (int mf = 0; mf < 2; ++mf)
#pragma unroll
                for (int nf = 0; nf < 2; ++nf)
                    acc[mf][nf] = __builtin_amdgcn_mfma_f32_16x16x32_bf16(a[ks][mf], bc[ks][nf], acc[mf][nf], 0, 0, 0);
        if (t < 26) {
#pragma unroll
            for (int ks = 0; ks < 2; ++ks)
#pragma unroll
                for (int nf = 0; nf < 2; ++nf)
                    bc[ks][nf] = bnx[ks][nf];
        }
    }

    // ---- epilogue: bf16 tile in LDS -> coalesced ch-last stores ----
    __syncthreads();
#pragma unroll
    for (int mf = 0; mf < 2; ++mf)
#pragma unroll
        for (int nf = 0; nf < 2; ++nf)
#pragma unroll
            for (int r = 0; r < 4; ++r) {
                const int mm = (mf0 + mf) * 16 + quad * 4 + r;
                if (mm < 56)
                    A[mm * 72 + (nf0 + nf) * 16 + lm] = (unsigned short)f2bf(acc[mf][nf][r]);
            }
    __syncthreads();
    const size_t pixb = ((size_t)(n * 16) + d) * HW + h * 56;
    for (int c = tid; c < 448; c += 256) {
        const int px = c >> 3, kk = c & 7;
        *(uint4*)(out1 + (pixb + px) * 64 + kk * 8) = *(const uint4*)&A[px * 72 + kk * 8];
    }
}

// ---------------- per-channel stats over bf16 ch-last ----------------------
__global__ __launch_bounds__(256) void k_stats_bf16(
    const unsigned short* __restrict__ src, float* __restrict__ sums, float* __restrict__ sqs)
{
    const int c4 = threadIdx.x & 15, part = threadIdx.x >> 4;   // 16 ci-quads, 16 parts
    const size_t base = (size_t)blockIdx.x * 1024;
    float s[4] = {0.f, 0.f, 0.f, 0.f}, q[4] = {0.f, 0.f, 0.f, 0.f};
#pragma unroll 4
    for (int i = 0; i < 64; ++i) {
        const size_t pix = base + part + (size_t)i * 16;
        const uint2 v = *(const uint2*)(src + pix * 64 + c4 * 4);
        const float f0 = bf2f(v.x & 0xffffu), f1 = bf2f(v.x >> 16);
        const float f2 = bf2f(v.y & 0xffffu), f3 = bf2f(v.y >> 16);
        s[0] += f0; q[0] = fmaf(f0, f0, q[0]);
        s[1] += f1; q[1] = fmaf(f1, f1, q[1]);
        s[2] += f2; q[2] = fmaf(f2, f2, q[2]);
        s[3] += f3; q[3] = fmaf(f3, f3, q[3]);
    }
    __shared__ float S[64], Q[64];
    if (threadIdx.x < 64) { S[threadIdx.x] = 0.f; Q[threadIdx.x] = 0.f; }
    __syncthreads();
#pragma unroll
    for (int e = 0; e < 4; ++e) {
        atomicAdd(&S[c4 * 4 + e], s[e]);
        atomicAdd(&Q[c4 * 4 + e], q[e]);
    }
    __syncthreads();
    if (threadIdx.x < 64) {
        atomicAdd(&sums[threadIdx.x], S[threadIdx.x]);
        atomicAdd(&sqs[threadIdx.x],  Q[threadIdx.x]);
    }
}

// ---------------- per-channel stats, NCDHW fp32 ----------------------------
__global__ __launch_bounds__(256) void k_stats(
    const float* __restrict__ src, float* __restrict__ sums, float* __restrict__ sqs)
{
    const int c = blockIdx.x, n = blockIdx.y;
    const float* p = src + ((size_t)n * 64 + c) * DHW;
    float s = 0.f, q = 0.f;
    for (int i = threadIdx.x; i < DHW; i += 256) {
        const float v = p[i];
        s += v; q = fmaf(v, v, q);
    }
    for (int o = 32; o > 0; o >>= 1) {
        s += __shfl_down(s, o);
        q += __shfl_down(q, o);
    }
    __shared__ float ls[4], lq[4];
    const int wv = threadIdx.x >> 6, lane = threadIdx.x & 63;
    if (lane == 0) { ls[wv] = s; lq[wv] = q; }
    __syncthreads();
    if (threadIdx.x == 0) {
        atomicAdd(&sums[c], ls[0] + ls[1] + ls[2] + ls[3]);
        atomicAdd(&sqs[c],  lq[0] + lq[1] + lq[2] + lq[3]);
    }
}

// ---------------- finalize BN: scale/shift ---------------------------------
__global__ void k_finalize(const float* __restrict__ sums, const float* __restrict__ sqs,
                           const float* __restrict__ gamma, const float* __restrict__ beta,
                           float* __restrict__ scale, float* __restrict__ shift)
{
    const int c = threadIdx.x; // 64 threads
    const float mean = sums[c] / CNT;
    const float var  = sqs[c] / CNT - mean * mean;
    const float sc   = gamma[c] * rsqrtf(var + 1e-5f);
    scale[c] = sc;
    shift[c] = fmaf(-mean, sc, beta[c]);
}

// -------- BN2 + residual + ReLU: dst = relu(bn(raw) + x)  (float4) ---------
__global__ __launch_bounds__(256) void k_residual(
    float4* __restrict__ dst, const float4* __restrict__ raw,
    const float4* __restrict__ x,
    const float* __restrict__ scale, const float* __restrict__ shift)
{
    const int i = blockIdx.x * 256 + threadIdx.x;   // < 6422528
    const int c = (i / 12544) & 63;                  // wave-uniform
    const float sc = scale[c], sh = shift[c];
    float4 v = raw[i];
    const float4 xv = x[i];
    v.x = fmaxf(fmaf(v.x, sc, sh) + xv.x, 0.f);
    v.y = fmaxf(fmaf(v.y, sc, sh) + xv.y, 0.f);
    v.z = fmaxf(fmaf(v.z, sc, sh) + xv.z, 0.f);
    v.w = fmaxf(fmaf(v.w, sc, sh) + xv.w, 0.f);
    dst[i] = v;
}

extern "C" void kernel_launch(void* const* d_in, const int* in_sizes, int n_in,
                              void* d_out, int out_size, void* d_ws, size_t ws_size,
                              hipStream_t stream) {
    const float* x     = (const float*)d_in[0];
    const float* w_off = (const float*)d_in[1];
    const float* b_off = (const float*)d_in[2];
    const float* w1    = (const float*)d_in[3];
    const float* w2    = (const float*)d_in[4];
    const float* b2    = (const float*)d_in[5];
    const float* g1    = (const float*)d_in[6];
    const float* be1   = (const float*)d_in[7];
    const float* g2    = (const float*)d_in[8];
    const float* be2   = (const float*)d_in[9];

    // ---- buffer plan ----
    // d_out: [0, 2*NEL) bytes      : out1 (deform result, bf16 ch-last) -- dead after k_conv<64>
    //        byte 52,000,000       : weight blocks (bf16) -- dead after k_conv<64>
    //        [4*NEL, ...) bytes    : off output (fp32, final)
    //        [0, 4*NEL) bytes      : final out (fp32), written LAST by k_residual
    // d_ws:  [0, 2*NEL) bytes      : xt (bf16 D-innermost x) -- dead after k_deform
    //        [0, 4*NEL) bytes      : raw (conv2 output fp32 NCDHW) overwrites xt
    //        [4*NEL, +2KiB)        : st stats block
    float* out     = (float*)d_out;
    float* off_out = out + NEL;
    unsigned short* out1 = (unsigned short*)d_out;
    unsigned short* wb   = (unsigned short*)(out + 13000000);  // byte 52,000,000
    unsigned short* BtO  = wb;
    unsigned short* Bt1  = BtO + 27648;
    unsigned short* Bt2  = Bt1 + 110592;

    unsigned short* xt  = (unsigned short*)d_ws;
    float*          raw = (float*)d_ws;
    float*          st  = (float*)d_ws + NEL;   // bytes [4*NEL, 4*NEL+2048)
    // st: 0 sum1 | 64 sq1 | 128 sc1 | 192 sh1 | 256 sum2 | 320 sq2 | 384 sc2 | 448 sh2

    hipMemsetAsync(st, 0, 512 * sizeof(float), stream);

    k_transpose<<<dim3(16, 8, 7), 256, 0, stream>>>(x, xt);
    k_wprep<<<432, 256, 0, stream>>>(w_off, w1, w2, BtO, Bt1, Bt2);

    const dim3 cgrid(56, 16, 8);   // h, d, n (decoded via xcd_decode inside)
    k_conv<8, false, true><<<cgrid, 256, 0, stream>>>(xt, BtO, b_off, nullptr, nullptr, off_out);
    k_deform<<<cgrid, 256, 0, stream>>>(xt, off_out, Bt1, out1);

    k_stats_bf16<<<392, 256, 0, stream>>>(out1, st + 0, st + 64);
    k_finalize<<<1, 64, 0, stream>>>(st + 0, st + 64, g1, be1, st + 128, st + 192);

    k_conv<64, true, false><<<cgrid, 256, 0, stream>>>(out1, Bt2, b2, st + 128, st + 192, raw);

    k_stats<<<dim3(64, 8), 256, 0, stream>>>(raw, st + 256, st + 320);
    k_finalize<<<1, 64, 0, stream>>>(st + 256, st + 320, g2, be2, st + 384, st + 448);
    k_residual<<<25088, 256, 0, stream>>>((float4*)out, (const float4*)raw, (const float4*)x, st + 384, st + 448);
}

// Round 4
// 910.117 us; speedup vs baseline: 2.2441x; 1.5874x over previous
//
#include <hip/hip_runtime.h>

#define HW 3136
#define DHW 50176
#define NEL 25690112   // 8*64*16*56*56
#define CNT 401408.0f  // 8*16*56*56

typedef __attribute__((ext_vector_type(8))) short          short8;
typedef __attribute__((ext_vector_type(8))) unsigned short ushort8;
typedef __attribute__((ext_vector_type(4))) float          f32x4;

__device__ __forceinline__ unsigned f2bf(float f) {
    union { float f; unsigned u; } v; v.f = f;
    return (v.u + 0x7FFFu + ((v.u >> 16) & 1u)) >> 16;   // RNE
}
__device__ __forceinline__ float bf2f(unsigned u) {
    union { unsigned u; float f; } v; v.u = u << 16;
    return v.f;
}

// XCD-aware swizzle for the 56x16x8 grids: XCD k (= bid % 8 round-robin)
// executes the contiguous logical range = ALL (h,d) of batch n=k, so each
// XCD's 4 MB L2 serves one n's xt/out1 slice (proven: FETCH 97->37 MB).
__device__ __forceinline__ void xcd_decode(int& h, int& d, int& n) {
    const int bid = blockIdx.x + 56 * (blockIdx.y + 16 * blockIdx.z);
    const int swz = (bid & 7) * 896 + (bid >> 3);
    h = swz % 56;
    const int dn = swz / 56;   // dn = d + 16*n, < 128
    d = dn & 15;
    n = dn >> 4;
}

// ---------------------------------------------------------------------------
// x (fp32 NCDHW) -> xt (bf16, D-innermost channels-last: [n][h*w][d][ci])
// ---------------------------------------------------------------------------
__global__ __launch_bounds__(256) void k_transpose(
    const float* __restrict__ x, unsigned short* __restrict__ xt)
{
    __shared__ unsigned lds[4][64 * 36];
    const int d = blockIdx.x, n = blockIdx.y, z = blockIdx.z;
    const int wave = threadIdx.x >> 6, lane = threadIdx.x & 63;
    const float* xb = x + (size_t)n * 64 * DHW + d * HW;
    unsigned short* xtb = xt + (size_t)n * DHW * 64;   // [hw][d][ci] inside
    unsigned* L = lds[wave];

    for (int c = z * 7 + wave; c < z * 7 + 7 && c < 49; c += 4) {
        const int P = c * 64;
#pragma unroll 4
        for (int cp = 0; cp < 32; ++cp) {
            const float a = xb[(size_t)(2 * cp) * DHW + P + lane];
            const float b = xb[(size_t)(2 * cp + 1) * DHW + P + lane];
            L[lane * 36 + cp] = f2bf(a) | (f2bf(b) << 16);
        }
#pragma unroll
        for (int k = 0; k < 8; ++k) {
            const int r = (lane >> 3) + 8 * k;          // pixel within 64-chunk
            const uint4 v = *(const uint4*)&L[r * 36 + 4 * (lane & 7)];
            *(uint4*)((char*)xtb + ((size_t)(P + r) * 16 + d) * 128 + (lane & 7) * 16) = v;
        }
    }
}

// ---------------------------------------------------------------------------
// Weight prep -- LANE-MAJOR PACKED fragment layout so each per-tap B load is
// one fully-coalesced 1 KB wave read (8 dense lines vs 16 half lines):
//   BtO[tap][ks][lane]{short8}           : 27*2*512 shorts
//   Bt1/Bt2[tap][rg][ks][lane]{short8}   : 27*4*2*512 shorts
// lane l of the load maps to row rg*16+(l&15), ci = ks*32+(l>>4)*8+e.
// ---------------------------------------------------------------------------
__global__ __launch_bounds__(256) void k_wprep(
    const float* __restrict__ w_off, const float* __restrict__ w1,
    const float* __restrict__ w2, unsigned short* __restrict__ BtO,
    unsigned short* __restrict__ Bt1, unsigned short* __restrict__ Bt2)
{
    const int i = blockIdx.x * 256 + threadIdx.x;
    if (i < 27648) {
        const int tap = i / 1024, r = i - tap * 1024;
        const int ks = r >> 9, r3 = r & 511, lane = r3 >> 3, e = r3 & 7;
        const int row = lane & 15;
        const int ci  = ks * 32 + (lane >> 4) * 8 + e;
        BtO[i] = (row < 8) ? (unsigned short)f2bf(w_off[(row * 64 + ci) * 27 + tap]) : 0;
    }
    if (i < 110592) {
        const int tap = i / 4096, r = i - tap * 4096;
        const int rg = r >> 10, r2 = r & 1023;
        const int ks = r2 >> 9, r3 = r2 & 511, lane = r3 >> 3, e = r3 & 7;
        const int co = rg * 16 + (lane & 15);
        const int ci = ks * 32 + (lane >> 4) * 8 + e;
        Bt1[i] = (unsigned short)f2bf(w1[(co * 64 + ci) * 27 + tap]);
        Bt2[i] = (unsigned short)f2bf(w2[(co * 64 + ci) * 27 + tap]);
    }
}

// ---------------------------------------------------------------------------
// Standard 3x3x3 conv via MFMA, LDS-staged. Block = (h, d, n), 256 thr.
// A-tile: 9 rows (3 dq x 3 hq) x 58 px x 64 ci bf16, row stride 72 shorts.
// DIN: input is D-innermost ([n][hw][d][ci]); else pixel-major ch-last.
// B loads use the lane-major packed layout (see k_wprep).
// ---------------------------------------------------------------------------
template<int NCO, bool BN, bool DIN>
__global__ __launch_bounds__(256) void k_conv(
    const unsigned short* __restrict__ src, const unsigned short* __restrict__ Bt,
    const float* __restrict__ bias, const float* __restrict__ scv,
    const float* __restrict__ shv, float* __restrict__ dst)
{
    __shared__ unsigned short A[538 * 72];   // 9*58=522 slots + 16 overrun pad
    int h, d, n;
    xcd_decode(h, d, n);
    const int tid = threadIdx.x;
    const int wave = tid >> 6, lane = tid & 63, lm = lane & 15, quad = lane >> 4;
    const int k8 = tid & 7;                  // fixed ci-chunk per thread

    float scr[8], shr[8];
    if constexpr (BN) {
#pragma unroll
        for (int e = 0; e < 8; ++e) { scr[e] = scv[k8 * 8 + e]; shr[e] = shv[k8 * 8 + e]; }
    }

    const unsigned short* snb = DIN ? (src + (size_t)n * DHW * 64)
                                    : (src + (size_t)(n * 16) * HW * 64);

    // ---- stage 4176 16B chunks ----
    for (int c = tid; c < 4176; c += 256) {
        const int idx = c >> 3;
        const int row = idx / 58, px = idx - row * 58;
        const int kd = row / 3, kh = row - kd * 3;
        const int dq = d + kd - 1, hq = h + kh - 1, wq = px - 1;
        ushort8 val = (ushort8)0;
        if (((unsigned)dq < 16u) & ((unsigned)hq < 56u) & ((unsigned)wq < 56u)) {
            const size_t off = DIN ? (((size_t)(hq * 56 + wq) * 16 + dq) * 64)
                                   : (((size_t)dq * HW + hq * 56 + wq) * 64);
            val = *(const ushort8*)(snb + off + k8 * 8);
            if constexpr (BN) {
#pragma unroll
                for (int e = 0; e < 8; ++e) {
                    const float f = fmaxf(fmaf(bf2f(val[e]), scr[e], shr[e]), 0.f);
                    val[e] = (unsigned short)f2bf(f);
                }
            }
        }
        *(ushort8*)&A[(size_t)idx * 72 + k8 * 8] = val;
    }
    __syncthreads();

    constexpr int NFm = (NCO == 8) ? 1 : 2;
    constexpr int NFn = (NCO == 8) ? 1 : 2;
    const int mf0 = (NCO == 8) ? wave : (wave & 1) * 2;
    const int nf0 = (NCO == 8) ? 0 : (wave >> 1) * 2;

    f32x4 acc[NFm][NFn];
#pragma unroll
    for (int i = 0; i < NFm; ++i)
#pragma unroll
        for (int j = 0; j < NFn; ++j) acc[i][j] = (f32x4){0.f, 0.f, 0.f, 0.f};

    // packed-B address for (tap, nf, ks)
    auto bofs = [&](int t, int nf, int ks) -> size_t {
        if constexpr (NCO == 8)
            return ((size_t)t * 2 + ks) * 512 + lane * 8;
        else
            return (((size_t)t * 4 + nf0 + nf) * 2 + ks) * 512 + lane * 8;
    };

    // ---- 27-tap K-loop, B software-pipelined ----
    short8 bc[2][NFn];
#pragma unroll
    for (int ks = 0; ks < 2; ++ks)
#pragma unroll
        for (int nf = 0; nf < NFn; ++nf)
            bc[ks][nf] = *(const short8*)(Bt + bofs(0, nf, ks));

#pragma unroll 1
    for (int t = 0; t < 27; ++t) {
        short8 bnx[2][NFn];
        if (t < 26) {
#pragma unroll
            for (int ks = 0; ks < 2; ++ks)
#pragma unroll
                for (int nf = 0; nf < NFn; ++nf)
                    bnx[ks][nf] = *(const short8*)(Bt + bofs(t + 1, nf, ks));
        }
        const int kd = t / 9, r9 = t - kd * 9, kh = r9 / 3, kw = r9 - kh * 3;
        const int rowb = (kd * 3 + kh) * 58 + kw;
        short8 a[2][NFm];
#pragma unroll
        for (int ks = 0; ks < 2; ++ks)
#pragma unroll
            for (int mf = 0; mf < NFm; ++mf)
                a[ks][mf] = *(const short8*)&A[(size_t)(rowb + (mf0 + mf) * 16 + lm) * 72 + ks * 32 + quad * 8];
#pragma unroll
        for (int ks = 0; ks < 2; ++ks)
#pragma unroll
            for (int mf = 0; mf < NFm; ++mf)
#pragma unroll
                for (int nf = 0; nf < NFn; ++nf)
                    acc[mf][nf] = __builtin_amdgcn_mfma_f32_16x16x32_bf16(a[ks][mf], bc[ks][nf], acc[mf][nf], 0, 0, 0);
        if (t < 26) {
#pragma unroll
            for (int ks = 0; ks < 2; ++ks)
#pragma unroll
                for (int nf = 0; nf < NFn; ++nf)
                    bc[ks][nf] = bnx[ks][nf];
        }
    }

    // ---- epilogue: LDS transpose -> fp32 NCDHW + bias ----
    __syncthreads();
    float* E = (float*)A;
    constexpr int CSTR = (NCO == 64) ? 65 : 17;
#pragma unroll
    for (int mf = 0; mf < NFm; ++mf)
#pragma unroll
        for (int nf = 0; nf < NFn; ++nf)
#pragma unroll
            for (int r = 0; r < 4; ++r) {
                const int mm = (mf0 + mf) * 16 + quad * 4 + r;
                if (mm < 56) E[mm * CSTR + (nf0 + nf) * 16 + lm] = acc[mf][nf][r];
            }
    __syncthreads();
    for (int f = tid; f < 56 * NCO; f += 256) {
        const int co = f / 56, w0 = f - co * 56;
        dst[((size_t)(n * NCO + co) * 16 + d) * HW + h * 56 + w0] = E[w0 * CSTR + co] + bias[co];
    }
}

// ---------------------------------------------------------------------------
// Temporal deformable conv. Staging BUILDS the interpolated field: row
// (kd, hq) holds g_kd[n, :, d, hq, :] at pos = off(d,hq,wq)+d+kd-1.
// Task order is g-MINOR: the 8 lanes of one pixel read the 8 chunks of the
// SAME 128-B line (dense gather: 8 lines/instr instead of 64 sparse).
// Output: bf16 ch-last [pixel][co] (D-major, feeds k_conv<64>).
// ---------------------------------------------------------------------------
__global__ __launch_bounds__(256) void k_deform(
    const unsigned short* __restrict__ xt, const float* __restrict__ offo,
    const unsigned short* __restrict__ Bt, unsigned short* __restrict__ out1)
{
    __shared__ unsigned short A[538 * 72];
    int h, d, n;
    xcd_decode(h, d, n);
    const int tid = threadIdx.x;
    const int wave = tid >> 6, lane = tid & 63, lm = lane & 15, quad = lane >> 4;

    // ---- prefetch the 6 offset values this thread needs (g-minor decode) ----
    float pv[6];
#pragma unroll
    for (int it = 0; it < 6; ++it) {
        const int c = tid + it * 256;
        float p = 0.f;
        if (c < 1392) {
            const int g = c & 7, pix = c >> 3;           // pix < 174
            const int hq3 = pix / 58, px = pix - hq3 * 58;
            const int habs = h + hq3 - 1, wq = px - 1;
            if (((unsigned)habs < 56u) & ((unsigned)wq < 56u))
                p = offo[((size_t)(n * 8 + g) * 16 + d) * HW + habs * 56 + wq] + (float)d;
        }
        pv[it] = p;
    }

    // ---- gather + lerp staging: 1392 tasks (174 px x 8 g), g-minor ----
#pragma unroll 2
    for (int it = 0; it < 6; ++it) {
        const int c = tid + it * 256;
        if (c >= 1392) break;
        const int g = c & 7, pix = c >> 3;
        const int hq3 = pix / 58, px = pix - hq3 * 58;
        const int habs = h + hq3 - 1, wq = px - 1;
        ushort8 o0 = (ushort8)0, o1 = (ushort8)0, o2 = (ushort8)0;
        if (((unsigned)habs < 56u) & ((unsigned)wq < 56u)) {
            const float p = pv[it];
            const float fl = floorf(p);
            const float fr = p - fl;
            const int i0 = (int)fl;
            // D-innermost: plane stride is 64 shorts (128 B); 8 g-lanes of one
            // pixel read the 8 consecutive 16-B chunks of each plane line.
            const unsigned short* cb = xt + ((size_t)n * HW + habs * 56 + wq) * (16 * 64) + g * 8;
            float s[4][8];
#pragma unroll
            for (int j = 0; j < 4; ++j) {
                const int dj = i0 - 1 + j;
                const bool ok = (unsigned)dj < 16u;
                const ushort8 v = *(const ushort8*)(cb + (size_t)(ok ? dj : 0) * 64);
#pragma unroll
                for (int e = 0; e < 8; ++e) s[j][e] = ok ? bf2f(v[e]) : 0.f;
            }
#pragma unroll
            for (int e = 0; e < 8; ++e) {
                o0[e] = (unsigned short)f2bf(fmaf(fr, s[1][e] - s[0][e], s[0][e]));
                o1[e] = (unsigned short)f2bf(fmaf(fr, s[2][e] - s[1][e], s[1][e]));
                o2[e] = (unsigned short)f2bf(fmaf(fr, s[3][e] - s[2][e], s[2][e]));
            }
        }
        const int sl = hq3 * 58 + px;
        *(ushort8*)&A[(size_t)(sl          ) * 72 + g * 8] = o0;   // kd=0 rows 0..2
        *(ushort8*)&A[(size_t)(sl + 3 * 58 ) * 72 + g * 8] = o1;   // kd=1 rows 3..5
        *(ushort8*)&A[(size_t)(sl + 6 * 58 ) * 72 + g * 8] = o2;   // kd=2 rows 6..8
    }
    __syncthreads();

    const int mf0 = (wave & 1) * 2, nf0 = (wave >> 1) * 2;
    f32x4 acc[2][2];
#pragma unroll
    for (int i = 0; i < 2; ++i)
#pragma unroll
        for (int j = 0; j < 2; ++j) acc[i][j] = (f32x4){0.f, 0.f, 0.f, 0.f};

    short8 bc[2][2];
#pragma unroll
    for (int ks = 0; ks < 2; ++ks)
#pragma unroll
        for (int nf = 0; nf < 2; ++nf)
            bc[ks][nf] = *(const short8*)(Bt + (((size_t)0 * 4 + nf0 + nf) * 2 + ks) * 512 + lane * 8);

#pragma unroll 1
    for (int t = 0; t < 27; ++t) {
        short8 bnx[2][2];
        if (t < 26) {
#pragma unroll
            for (int ks = 0; ks < 2; ++ks)
#pragma unroll
                for (int nf = 0; nf < 2; ++nf)
                    bnx[ks][nf] = *(const short8*)(Bt + (((size_t)(t + 1) * 4 + nf0 + nf) * 2 + ks) * 512 + lane * 8);
        }
        const int kd = t / 9, r9 = t - kd * 9, kh = r9 / 3, kw = r9 - kh * 3;
        const int rowb = (kd * 3 + kh) * 58 + kw;
        short8 a[2][2];
#pragma unroll
        for (int ks = 0; ks < 2; ++ks)
#pragma unroll
            for (int mf = 0; mf < 2; ++mf)
                a[ks][mf] = *(const short8*)&A[(size_t)(rowb + (mf0 + mf) * 16 + lm) * 72 + ks * 32 + quad * 8];
#pragma unroll
        for (int ks = 0; ks < 2; ++ks)
#pragma unroll
            for (int mf = 0; mf < 2; ++mf)
#pragma unroll
                for (int nf = 0; nf < 2; ++nf)
                    acc[mf][nf] = __builtin_amdgcn_mfma_f32_16x16x32_bf16(a[ks][mf], bc[ks][nf], acc[mf][nf], 0, 0, 0);
        if (t < 26) {
#pragma unroll
            for (int ks = 0; ks < 2; ++ks)
#pragma unroll
                for (int nf = 0; nf < 2; ++nf)
                    bc[ks][nf] = bnx[ks][nf];
        }
    }

    // ---- epilogue: bf16 tile in LDS -> coalesced ch-last stores ----
    __syncthreads();
#pragma unroll
    for (int mf = 0; mf < 2; ++mf)
#pragma unroll
        for (int nf = 0; nf < 2; ++nf)
#pragma unroll
            for (int r = 0; r < 4; ++r) {
                const int mm = (mf0 + mf) * 16 + quad * 4 + r;
                if (mm < 56)
                    A[mm * 72 + (nf0 + nf) * 16 + lm] = (unsigned short)f2bf(acc[mf][nf][r]);
            }
    __syncthreads();
    const size_t pixb = ((size_t)(n * 16) + d) * HW + h * 56;
    for (int c = tid; c < 448; c += 256) {
        const int px = c >> 3, kk = c & 7;
        *(uint4*)(out1 + (pixb + px) * 64 + kk * 8) = *(const uint4*)&A[px * 72 + kk * 8];
    }
}

// ---------------- per-channel stats over bf16 ch-last ----------------------
__global__ __launch_bounds__(256) void k_stats_bf16(
    const unsigned short* __restrict__ src, float* __restrict__ sums, float* __restrict__ sqs)
{
    const int c4 = threadIdx.x & 15, part = threadIdx.x >> 4;   // 16 ci-quads, 16 parts
    const size_t base = (size_t)blockIdx.x * 1024;
    float s[4] = {0.f, 0.f, 0.f, 0.f}, q[4] = {0.f, 0.f, 0.f, 0.f};
#pragma unroll 4
    for (int i = 0; i < 64; ++i) {
        const size_t pix = base + part + (size_t)i * 16;
        const uint2 v = *(const uint2*)(src + pix * 64 + c4 * 4);
        const float f0 = bf2f(v.x & 0xffffu), f1 = bf2f(v.x >> 16);
        const float f2 = bf2f(v.y & 0xffffu), f3 = bf2f(v.y >> 16);
        s[0] += f0; q[0] = fmaf(f0, f0, q[0]);
        s[1] += f1; q[1] = fmaf(f1, f1, q[1]);
        s[2] += f2; q[2] = fmaf(f2, f2, q[2]);
        s[3] += f3; q[3] = fmaf(f3, f3, q[3]);
    }
    __shared__ float S[64], Q[64];
    if (threadIdx.x < 64) { S[threadIdx.x] = 0.f; Q[threadIdx.x] = 0.f; }
    __syncthreads();
#pragma unroll
    for (int e = 0; e < 4; ++e) {
        atomicAdd(&S[c4 * 4 + e], s[e]);
        atomicAdd(&Q[c4 * 4 + e], q[e]);
    }
    __syncthreads();
    if (threadIdx.x < 64) {
        atomicAdd(&sums[threadIdx.x], S[threadIdx.x]);
        atomicAdd(&sqs[threadIdx.x],  Q[threadIdx.x]);
    }
}

// ---------------- per-channel stats, NCDHW fp32 ----------------------------
__global__ __launch_bounds__(256) void k_stats(
    const float* __restrict__ src, float* __restrict__ sums, float* __restrict__ sqs)
{
    const int c = blockIdx.x, n = blockIdx.y;
    const float* p = src + ((size_t)n * 64 + c) * DHW;
    float s = 0.f, q = 0.f;
    for (int i = threadIdx.x; i < DHW; i += 256) {
        const float v = p[i];
        s += v; q = fmaf(v, v, q);
    }
    for (int o = 32; o > 0; o >>= 1) {
        s += __shfl_down(s, o);
        q += __shfl_down(q, o);
    }
    __shared__ float ls[4], lq[4];
    const int wv = threadIdx.x >> 6, lane = threadIdx.x & 63;
    if (lane == 0) { ls[wv] = s; lq[wv] = q; }
    __syncthreads();
    if (threadIdx.x == 0) {
        atomicAdd(&sums[c], ls[0] + ls[1] + ls[2] + ls[3]);
        atomicAdd(&sqs[c],  lq[0] + lq[1] + lq[2] + lq[3]);
    }
}

// ---------------- finalize BN: scale/shift ---------------------------------
__global__ void k_finalize(const float* __restrict__ sums, const float* __restrict__ sqs,
                           const float* __restrict__ gamma, const float* __restrict__ beta,
                           float* __restrict__ scale, float* __restrict__ shift)
{
    const int c = threadIdx.x; // 64 threads
    const float mean = sums[c] / CNT;
    const float var  = sqs[c] / CNT - mean * mean;
    const float sc   = gamma[c] * rsqrtf(var + 1e-5f);
    scale[c] = sc;
    shift[c] = fmaf(-mean, sc, beta[c]);
}

// -------- BN2 + residual + ReLU: dst = relu(bn(raw) + x)  (float4) ---------
__global__ __launch_bounds__(256) void k_residual(
    float4* __restrict__ dst, const float4* __restrict__ raw,
    const float4* __restrict__ x,
    const float* __restrict__ scale, const float* __restrict__ shift)
{
    const int i = blockIdx.x * 256 + threadIdx.x;   // < 6422528
    const int c = (i / 12544) & 63;                  // wave-uniform
    const float sc = scale[c], sh = shift[c];
    float4 v = raw[i];
    const float4 xv = x[i];
    v.x = fmaxf(fmaf(v.x, sc, sh) + xv.x, 0.f);
    v.y = fmaxf(fmaf(v.y, sc, sh) + xv.y, 0.f);
    v.z = fmaxf(fmaf(v.z, sc, sh) + xv.z, 0.f);
    v.w = fmaxf(fmaf(v.w, sc, sh) + xv.w, 0.f);
    dst[i] = v;
}

extern "C" void kernel_launch(void* const* d_in, const int* in_sizes, int n_in,
                              void* d_out, int out_size, void* d_ws, size_t ws_size,
                              hipStream_t stream) {
    const float* x     = (const float*)d_in[0];
    const float* w_off = (const float*)d_in[1];
    const float* b_off = (const float*)d_in[2];
    const float* w1    = (const float*)d_in[3];
    const float* w2    = (const float*)d_in[4];
    const float* b2    = (const float*)d_in[5];
    const float* g1    = (const float*)d_in[6];
    const float* be1   = (const float*)d_in[7];
    const float* g2    = (const float*)d_in[8];
    const float* be2   = (const float*)d_in[9];

    // ---- buffer plan ----
    // d_out: [0, 2*NEL) bytes      : out1 (deform result, bf16 ch-last) -- dead after k_conv<64>
    //        byte 52,000,000       : weight blocks (bf16) -- dead after k_conv<64>
    //        [4*NEL, ...) bytes    : off output (fp32, final)
    //        [0, 4*NEL) bytes      : final out (fp32), written LAST by k_residual
    // d_ws:  [0, 2*NEL) bytes      : xt (bf16 D-innermost x) -- dead after k_deform
    //        [0, 4*NEL) bytes      : raw (conv2 output fp32 NCDHW) overwrites xt
    //        [4*NEL, +2KiB)        : st stats block
    float* out     = (float*)d_out;
    float* off_out = out + NEL;
    unsigned short* out1 = (unsigned short*)d_out;
    unsigned short* wb   = (unsigned short*)(out + 13000000);  // byte 52,000,000
    unsigned short* BtO  = wb;
    unsigned short* Bt1  = BtO + 27648;
    unsigned short* Bt2  = Bt1 + 110592;

    unsigned short* xt  = (unsigned short*)d_ws;
    float*          raw = (float*)d_ws;
    float*          st  = (float*)d_ws + NEL;   // bytes [4*NEL, 4*NEL+2048)
    // st: 0 sum1 | 64 sq1 | 128 sc1 | 192 sh1 | 256 sum2 | 320 sq2 | 384 sc2 | 448 sh2

    hipMemsetAsync(st, 0, 512 * sizeof(float), stream);

    k_transpose<<<dim3(16, 8, 7), 256, 0, stream>>>(x, xt);
    k_wprep<<<432, 256, 0, stream>>>(w_off, w1, w2, BtO, Bt1, Bt2);

    const dim3 cgrid(56, 16, 8);   // h, d, n (decoded via xcd_decode inside)
    k_conv<8, false, true><<<cgrid, 256, 0, stream>>>(xt, BtO, b_off, nullptr, nullptr, off_out);
    k_deform<<<cgrid, 256, 0, stream>>>(xt, off_out, Bt1, out1);

    k_stats_bf16<<<392, 256, 0, stream>>>(out1, st + 0, st + 64);
    k_finalize<<<1, 64, 0, stream>>>(st + 0, st + 64, g1, be1, st + 128, st + 192);

    k_conv<64, true, false><<<cgrid, 256, 0, stream>>>(out1, Bt2, b2, st + 128, st + 192, raw);

    k_stats<<<dim3(64, 8), 256, 0, stream>>>(raw, st + 256, st + 320);
    k_finalize<<<1, 64, 0, stream>>>(st + 256, st + 320, g2, be2, st + 384, st + 448);
    k_residual<<<25088, 256, 0, stream>>>((float4*)out, (const float4*)raw, (const float4*)x, st + 384, st + 448);
}

// Round 5
// 809.235 us; speedup vs baseline: 2.5239x; 1.1247x over previous
//
#include <hip/hip_runtime.h>

#define HW 3136
#define DHW 50176
#define NEL 25690112   // 8*64*16*56*56
#define CNT 401408.0f  // 8*16*56*56

typedef __attribute__((ext_vector_type(8))) short          short8;
typedef __attribute__((ext_vector_type(8))) unsigned short ushort8;
typedef __attribute__((ext_vector_type(4))) float          f32x4;

__device__ __forceinline__ unsigned f2bf(float f) {
    union { float f; unsigned u; } v; v.f = f;
    return (v.u + 0x7FFFu + ((v.u >> 16) & 1u)) >> 16;   // RNE
}
__device__ __forceinline__ float bf2f(unsigned u) {
    union { unsigned u; float f; } v; v.u = u << 16;
    return v.f;
}

// XCD-aware swizzle for the 56x16x8 grids: XCD k (= bid % 8 round-robin)
// executes the contiguous logical range = ALL (h,d) of batch n=k, so each
// XCD's 4 MB L2 serves one n's xt/out1 slice (proven: FETCH 97->37 MB).
__device__ __forceinline__ void xcd_decode(int& h, int& d, int& n) {
    const int bid = blockIdx.x + 56 * (blockIdx.y + 16 * blockIdx.z);
    const int swz = (bid & 7) * 896 + (bid >> 3);
    h = swz % 56;
    const int dn = swz / 56;   // dn = d + 16*n, < 128
    d = dn & 15;
    n = dn >> 4;
}

// ---------------------------------------------------------------------------
// x (fp32 NCDHW) -> xt (bf16, D-innermost channels-last: [n][h*w][d][ci])
// ---------------------------------------------------------------------------
__global__ __launch_bounds__(256) void k_transpose(
    const float* __restrict__ x, unsigned short* __restrict__ xt)
{
    __shared__ unsigned lds[4][64 * 36];
    const int d = blockIdx.x, n = blockIdx.y, z = blockIdx.z;
    const int wave = threadIdx.x >> 6, lane = threadIdx.x & 63;
    const float* xb = x + (size_t)n * 64 * DHW + d * HW;
    unsigned short* xtb = xt + (size_t)n * DHW * 64;   // [hw][d][ci] inside
    unsigned* L = lds[wave];

    for (int c = z * 7 + wave; c < z * 7 + 7 && c < 49; c += 4) {
        const int P = c * 64;
#pragma unroll 4
        for (int cp = 0; cp < 32; ++cp) {
            const float a = xb[(size_t)(2 * cp) * DHW + P + lane];
            const float b = xb[(size_t)(2 * cp + 1) * DHW + P + lane];
            L[lane * 36 + cp] = f2bf(a) | (f2bf(b) << 16);
        }
#pragma unroll
        for (int k = 0; k < 8; ++k) {
            const int r = (lane >> 3) + 8 * k;          // pixel within 64-chunk
            const uint4 v = *(const uint4*)&L[r * 36 + 4 * (lane & 7)];
            *(uint4*)((char*)xtb + ((size_t)(P + r) * 16 + d) * 128 + (lane & 7) * 16) = v;
        }
    }
}

// ---------------------------------------------------------------------------
// Weight prep -- LANE-MAJOR PACKED fragment layout so each per-tap B load is
// one fully-coalesced 1 KB wave read (8 dense lines vs 16 half lines):
//   BtO[tap][ks][lane]{short8}           : 27*2*512 shorts
//   Bt1/Bt2[tap][rg][ks][lane]{short8}   : 27*4*2*512 shorts
// lane l of the load maps to row rg*16+(l&15), ci = ks*32+(l>>4)*8+e.
// ---------------------------------------------------------------------------
__global__ __launch_bounds__(256) void k_wprep(
    const float* __restrict__ w_off, const float* __restrict__ w1,
    const float* __restrict__ w2, unsigned short* __restrict__ BtO,
    unsigned short* __restrict__ Bt1, unsigned short* __restrict__ Bt2)
{
    const int i = blockIdx.x * 256 + threadIdx.x;
    if (i < 27648) {
        const int tap = i / 1024, r = i - tap * 1024;
        const int ks = r >> 9, r3 = r & 511, lane = r3 >> 3, e = r3 & 7;
        const int row = lane & 15;
        const int ci  = ks * 32 + (lane >> 4) * 8 + e;
        BtO[i] = (row < 8) ? (unsigned short)f2bf(w_off[(row * 64 + ci) * 27 + tap]) : 0;
    }
    if (i < 110592) {
        const int tap = i / 4096, r = i - tap * 4096;
        const int rg = r >> 10, r2 = r & 1023;
        const int ks = r2 >> 9, r3 = r2 & 511, lane = r3 >> 3, e = r3 & 7;
        const int co = rg * 16 + (lane & 15);
        const int ci = ks * 32 + (lane >> 4) * 8 + e;
        Bt1[i] = (unsigned short)f2bf(w1[(co * 64 + ci) * 27 + tap]);
        Bt2[i] = (unsigned short)f2bf(w2[(co * 64 + ci) * 27 + tap]);
    }
}

// ---------------------------------------------------------------------------
// Standard 3x3x3 conv via MFMA, LDS-staged. Block = (h, d, n).
// A-tile: 9 rows (3 dq x 3 hq) x 58 px x 64 ci bf16, row stride 72 shorts.
// NCO==8 : 256 thr, 4 waves x (1 mf x 1 nf).
// NCO==64: 512 thr, 8 waves x (2 mf x 1 nf) -- same per-block B traffic as
//          the 4-wave 2x2 layout, but 16 waves/CU (50% occ) for latency
//          hiding at UNCHANGED LDS (round-1 lesson: don't shrink the tile).
// ---------------------------------------------------------------------------
template<int NCO, bool BN, bool DIN>
__global__ __launch_bounds__((NCO == 8) ? 256 : 512) void k_conv(
    const unsigned short* __restrict__ src, const unsigned short* __restrict__ Bt,
    const float* __restrict__ bias, const float* __restrict__ scv,
    const float* __restrict__ shv, float* __restrict__ dst)
{
    constexpr int NT = (NCO == 8) ? 256 : 512;
    __shared__ unsigned short A[538 * 72];   // 9*58=522 slots + 16 overrun pad
    int h, d, n;
    xcd_decode(h, d, n);
    const int tid = threadIdx.x;
    const int wave = tid >> 6, lane = tid & 63, lm = lane & 15, quad = lane >> 4;
    const int k8 = tid & 7;                  // fixed ci-chunk per thread

    float scr[8], shr[8];
    if constexpr (BN) {
#pragma unroll
        for (int e = 0; e < 8; ++e) { scr[e] = scv[k8 * 8 + e]; shr[e] = shv[k8 * 8 + e]; }
    }

    const unsigned short* snb = DIN ? (src + (size_t)n * DHW * 64)
                                    : (src + (size_t)(n * 16) * HW * 64);

    // ---- stage 4176 16B chunks ----
    for (int c = tid; c < 4176; c += NT) {
        const int idx = c >> 3;
        const int row = idx / 58, px = idx - row * 58;
        const int kd = row / 3, kh = row - kd * 3;
        const int dq = d + kd - 1, hq = h + kh - 1, wq = px - 1;
        ushort8 val = (ushort8)0;
        if (((unsigned)dq < 16u) & ((unsigned)hq < 56u) & ((unsigned)wq < 56u)) {
            const size_t off = DIN ? (((size_t)(hq * 56 + wq) * 16 + dq) * 64)
                                   : (((size_t)dq * HW + hq * 56 + wq) * 64);
            val = *(const ushort8*)(snb + off + k8 * 8);
            if constexpr (BN) {
#pragma unroll
                for (int e = 0; e < 8; ++e) {
                    const float f = fmaxf(fmaf(bf2f(val[e]), scr[e], shr[e]), 0.f);
                    val[e] = (unsigned short)f2bf(f);
                }
            }
        }
        *(ushort8*)&A[(size_t)idx * 72 + k8 * 8] = val;
    }
    __syncthreads();

    constexpr int NFm = (NCO == 8) ? 1 : 2;
    const int mf0 = (NCO == 8) ? wave : (wave & 1) * 2;
    const int nf0 = (NCO == 8) ? 0 : (wave >> 1);        // 0..3 (single n-frag)

    f32x4 acc[NFm];
#pragma unroll
    for (int i = 0; i < NFm; ++i) acc[i] = (f32x4){0.f, 0.f, 0.f, 0.f};

    // packed-B address for (tap, ks)
    auto bofs = [&](int t, int ks) -> size_t {
        if constexpr (NCO == 8)
            return ((size_t)t * 2 + ks) * 512 + lane * 8;
        else
            return (((size_t)t * 4 + nf0) * 2 + ks) * 512 + lane * 8;
    };

    // ---- 27-tap K-loop, B software-pipelined ----
    short8 bc[2];
#pragma unroll
    for (int ks = 0; ks < 2; ++ks) bc[ks] = *(const short8*)(Bt + bofs(0, ks));

#pragma unroll 1
    for (int t = 0; t < 27; ++t) {
        short8 bnx[2];
        if (t < 26) {
#pragma unroll
            for (int ks = 0; ks < 2; ++ks) bnx[ks] = *(const short8*)(Bt + bofs(t + 1, ks));
        }
        const int kd = t / 9, r9 = t - kd * 9, kh = r9 / 3, kw = r9 - kh * 3;
        const int rowb = (kd * 3 + kh) * 58 + kw;
        short8 a[2][NFm];
#pragma unroll
        for (int ks = 0; ks < 2; ++ks)
#pragma unroll
            for (int mf = 0; mf < NFm; ++mf)
                a[ks][mf] = *(const short8*)&A[(size_t)(rowb + (mf0 + mf) * 16 + lm) * 72 + ks * 32 + quad * 8];
#pragma unroll
        for (int ks = 0; ks < 2; ++ks)
#pragma unroll
            for (int mf = 0; mf < NFm; ++mf)
                acc[mf] = __builtin_amdgcn_mfma_f32_16x16x32_bf16(a[ks][mf], bc[ks], acc[mf], 0, 0, 0);
        if (t < 26) {
#pragma unroll
            for (int ks = 0; ks < 2; ++ks) bc[ks] = bnx[ks];
        }
    }

    // ---- epilogue: LDS transpose -> fp32 NCDHW + bias ----
    __syncthreads();
    float* E = (float*)A;
    constexpr int CSTR = (NCO == 64) ? 65 : 17;
#pragma unroll
    for (int mf = 0; mf < NFm; ++mf)
#pragma unroll
        for (int r = 0; r < 4; ++r) {
            const int mm = (mf0 + mf) * 16 + quad * 4 + r;
            if (mm < 56) E[mm * CSTR + nf0 * 16 + lm] = acc[mf][r];
        }
    __syncthreads();
    for (int f = tid; f < 56 * NCO; f += NT) {
        const int co = f / 56, w0 = f - co * 56;
        dst[((size_t)(n * NCO + co) * 16 + d) * HW + h * 56 + w0] = E[w0 * CSTR + co] + bias[co];
    }
}

// ---------------------------------------------------------------------------
// Temporal deformable conv. 512 thr, 8 waves x (2 mf x 1 nf).
// Staging BUILDS the interpolated field: row (kd, hq) holds
// g_kd[n, :, d, hq, :] at pos = off(d,hq,wq)+d+kd-1.
// Task order g-MINOR: the 8 lanes of one pixel read the 8 chunks of the
// SAME 128-B line (dense gather). Output: bf16 ch-last [pixel][co].
// ---------------------------------------------------------------------------
__global__ __launch_bounds__(512) void k_deform(
    const unsigned short* __restrict__ xt, const float* __restrict__ offo,
    const unsigned short* __restrict__ Bt, unsigned short* __restrict__ out1)
{
    __shared__ unsigned short A[538 * 72];
    int h, d, n;
    xcd_decode(h, d, n);
    const int tid = threadIdx.x;
    const int wave = tid >> 6, lane = tid & 63, lm = lane & 15, quad = lane >> 4;

    // ---- prefetch the 3 offset values this thread needs (g-minor decode) ----
    float pv[3];
#pragma unroll
    for (int it = 0; it < 3; ++it) {
        const int c = tid + it * 512;
        float p = 0.f;
        if (c < 1392) {
            const int g = c & 7, pix = c >> 3;           // pix < 174
            const int hq3 = pix / 58, px = pix - hq3 * 58;
            const int habs = h + hq3 - 1, wq = px - 1;
            if (((unsigned)habs < 56u) & ((unsigned)wq < 56u))
                p = offo[((size_t)(n * 8 + g) * 16 + d) * HW + habs * 56 + wq] + (float)d;
        }
        pv[it] = p;
    }

    // ---- gather + lerp staging: 1392 tasks (174 px x 8 g), g-minor ----
#pragma unroll
    for (int it = 0; it < 3; ++it) {
        const int c = tid + it * 512;
        if (c >= 1392) break;
        const int g = c & 7, pix = c >> 3;
        const int hq3 = pix / 58, px = pix - hq3 * 58;
        const int habs = h + hq3 - 1, wq = px - 1;
        ushort8 o0 = (ushort8)0, o1 = (ushort8)0, o2 = (ushort8)0;
        if (((unsigned)habs < 56u) & ((unsigned)wq < 56u)) {
            const float p = pv[it];
            const float fl = floorf(p);
            const float fr = p - fl;
            const int i0 = (int)fl;
            // D-innermost: plane stride is 64 shorts (128 B); 8 g-lanes of one
            // pixel read the 8 consecutive 16-B chunks of each plane line.
            const unsigned short* cb = xt + ((size_t)n * HW + habs * 56 + wq) * (16 * 64) + g * 8;
            float s[4][8];
#pragma unroll
            for (int j = 0; j < 4; ++j) {
                const int dj = i0 - 1 + j;
                const bool ok = (unsigned)dj < 16u;
                const ushort8 v = *(const ushort8*)(cb + (size_t)(ok ? dj : 0) * 64);
#pragma unroll
                for (int e = 0; e < 8; ++e) s[j][e] = ok ? bf2f(v[e]) : 0.f;
            }
#pragma unroll
            for (int e = 0; e < 8; ++e) {
                o0[e] = (unsigned short)f2bf(fmaf(fr, s[1][e] - s[0][e], s[0][e]));
                o1[e] = (unsigned short)f2bf(fmaf(fr, s[2][e] - s[1][e], s[1][e]));
                o2[e] = (unsigned short)f2bf(fmaf(fr, s[3][e] - s[2][e], s[2][e]));
            }
        }
        const int sl = hq3 * 58 + px;
        *(ushort8*)&A[(size_t)(sl          ) * 72 + g * 8] = o0;   // kd=0 rows 0..2
        *(ushort8*)&A[(size_t)(sl + 3 * 58 ) * 72 + g * 8] = o1;   // kd=1 rows 3..5
        *(ushort8*)&A[(size_t)(sl + 6 * 58 ) * 72 + g * 8] = o2;   // kd=2 rows 6..8
    }
    __syncthreads();

    const int mf0 = (wave & 1) * 2, nf0 = wave >> 1;     // 2 mf x 1 nf per wave
    f32x4 acc[2];
    acc[0] = (f32x4){0.f, 0.f, 0.f, 0.f};
    acc[1] = (f32x4){0.f, 0.f, 0.f, 0.f};

    short8 bc[2];
#pragma unroll
    for (int ks = 0; ks < 2; ++ks)
        bc[ks] = *(const short8*)(Bt + (((size_t)0 * 4 + nf0) * 2 + ks) * 512 + lane * 8);

#pragma unroll 1
    for (int t = 0; t < 27; ++t) {
        short8 bnx[2];
        if (t < 26) {
#pragma unroll
            for (int ks = 0; ks < 2; ++ks)
                bnx[ks] = *(const short8*)(Bt + (((size_t)(t + 1) * 4 + nf0) * 2 + ks) * 512 + lane * 8);
        }
        const int kd = t / 9, r9 = t - kd * 9, kh = r9 / 3, kw = r9 - kh * 3;
        const int rowb = (kd * 3 + kh) * 58 + kw;
        short8 a[2][2];
#pragma unroll
        for (int ks = 0; ks < 2; ++ks)
#pragma unroll
            for (int mf = 0; mf < 2; ++mf)
                a[ks][mf] = *(const short8*)&A[(size_t)(rowb + (mf0 + mf) * 16 + lm) * 72 + ks * 32 + quad * 8];
#pragma unroll
        for (int ks = 0; ks < 2; ++ks)
#pragma unroll
            for (int mf = 0; mf < 2; ++mf)
                acc[mf] = __builtin_amdgcn_mfma_f32_16x16x32_bf16(a[ks][mf], bc[ks], acc[mf], 0, 0, 0);
        if (t < 26) {
#pragma unroll
            for (int ks = 0; ks < 2; ++ks) bc[ks] = bnx[ks];
        }
    }

    // ---- epilogue: bf16 tile in LDS -> coalesced ch-last stores ----
    __syncthreads();
#pragma unroll
    for (int mf = 0; mf < 2; ++mf)
#pragma unroll
        for (int r = 0; r < 4; ++r) {
            const int mm = (mf0 + mf) * 16 + quad * 4 + r;
            if (mm < 56)
                A[mm * 72 + nf0 * 16 + lm] = (unsigned short)f2bf(acc[mf][r]);
        }
    __syncthreads();
    const size_t pixb = ((size_t)(n * 16) + d) * HW + h * 56;
    if (tid < 448) {
        const int px = tid >> 3, kk = tid & 7;
        *(uint4*)(out1 + (pixb + px) * 64 + kk * 8) = *(const uint4*)&A[px * 72 + kk * 8];
    }
}

// ---------------- per-channel stats over bf16 ch-last ----------------------
__global__ __launch_bounds__(256) void k_stats_bf16(
    const unsigned short* __restrict__ src, float* __restrict__ sums, float* __restrict__ sqs)
{
    const int c4 = threadIdx.x & 15, part = threadIdx.x >> 4;   // 16 ci-quads, 16 parts
    const size_t base = (size_t)blockIdx.x * 1024;
    float s[4] = {0.f, 0.f, 0.f, 0.f}, q[4] = {0.f, 0.f, 0.f, 0.f};
#pragma unroll 4
    for (int i = 0; i < 64; ++i) {
        const size_t pix = base + part + (size_t)i * 16;
        const uint2 v = *(const uint2*)(src + pix * 64 + c4 * 4);
        const float f0 = bf2f(v.x & 0xffffu), f1 = bf2f(v.x >> 16);
        const float f2 = bf2f(v.y & 0xffffu), f3 = bf2f(v.y >> 16);
        s[0] += f0; q[0] = fmaf(f0, f0, q[0]);
        s[1] += f1; q[1] = fmaf(f1, f1, q[1]);
        s[2] += f2; q[2] = fmaf(f2, f2, q[2]);
        s[3] += f3; q[3] = fmaf(f3, f3, q[3]);
    }
    __shared__ float S[64], Q[64];
    if (threadIdx.x < 64) { S[threadIdx.x] = 0.f; Q[threadIdx.x] = 0.f; }
    __syncthreads();
#pragma unroll
    for (int e = 0; e < 4; ++e) {
        atomicAdd(&S[c4 * 4 + e], s[e]);
        atomicAdd(&Q[c4 * 4 + e], q[e]);
    }
    __syncthreads();
    if (threadIdx.x < 64) {
        atomicAdd(&sums[threadIdx.x], S[threadIdx.x]);
        atomicAdd(&sqs[threadIdx.x],  Q[threadIdx.x]);
    }
}

// ---------------- per-channel stats, NCDHW fp32 ----------------------------
__global__ __launch_bounds__(256) void k_stats(
    const float* __restrict__ src, float* __restrict__ sums, float* __restrict__ sqs)
{
    const int c = blockIdx.x, n = blockIdx.y;
    const float* p = src + ((size_t)n * 64 + c) * DHW;
    float s = 0.f, q = 0.f;
    for (int i = threadIdx.x; i < DHW; i += 256) {
        const float v = p[i];
        s += v; q = fmaf(v, v, q);
    }
    for (int o = 32; o > 0; o >>= 1) {
        s += __shfl_down(s, o);
        q += __shfl_down(q, o);
    }
    __shared__ float ls[4], lq[4];
    const int wv = threadIdx.x >> 6, lane = threadIdx.x & 63;
    if (lane == 0) { ls[wv] = s; lq[wv] = q; }
    __syncthreads();
    if (threadIdx.x == 0) {
        atomicAdd(&sums[c], ls[0] + ls[1] + ls[2] + ls[3]);
        atomicAdd(&sqs[c],  lq[0] + lq[1] + lq[2] + lq[3]);
    }
}

// ---------------- finalize BN: scale/shift ---------------------------------
__global__ void k_finalize(const float* __restrict__ sums, const float* __restrict__ sqs,
                           const float* __restrict__ gamma, const float* __restrict__ beta,
                           float* __restrict__ scale, float* __restrict__ shift)
{
    const int c = threadIdx.x; // 64 threads
    const float mean = sums[c] / CNT;
    const float var  = sqs[c] / CNT - mean * mean;
    const float sc   = gamma[c] * rsqrtf(var + 1e-5f);
    scale[c] = sc;
    shift[c] = fmaf(-mean, sc, beta[c]);
}

// -------- BN2 + residual + ReLU: dst = relu(bn(raw) + x)  (float4) ---------
__global__ __launch_bounds__(256) void k_residual(
    float4* __restrict__ dst, const float4* __restrict__ raw,
    const float4* __restrict__ x,
    const float* __restrict__ scale, const float* __restrict__ shift)
{
    const int i = blockIdx.x * 256 + threadIdx.x;   // < 6422528
    const int c = (i / 12544) & 63;                  // wave-uniform
    const float sc = scale[c], sh = shift[c];
    float4 v = raw[i];
    const float4 xv = x[i];
    v.x = fmaxf(fmaf(v.x, sc, sh) + xv.x, 0.f);
    v.y = fmaxf(fmaf(v.y, sc, sh) + xv.y, 0.f);
    v.z = fmaxf(fmaf(v.z, sc, sh) + xv.z, 0.f);
    v.w = fmaxf(fmaf(v.w, sc, sh) + xv.w, 0.f);
    dst[i] = v;
}

extern "C" void kernel_launch(void* const* d_in, const int* in_sizes, int n_in,
                              void* d_out, int out_size, void* d_ws, size_t ws_size,
                              hipStream_t stream) {
    const float* x     = (const float*)d_in[0];
    const float* w_off = (const float*)d_in[1];
    const float* b_off = (const float*)d_in[2];
    const float* w1    = (const float*)d_in[3];
    const float* w2    = (const float*)d_in[4];
    const float* b2    = (const float*)d_in[5];
    const float* g1    = (const float*)d_in[6];
    const float* be1   = (const float*)d_in[7];
    const float* g2    = (const float*)d_in[8];
    const float* be2   = (const float*)d_in[9];

    // ---- buffer plan ----
    // d_out: [0, 2*NEL) bytes      : out1 (deform result, bf16 ch-last) -- dead after k_conv<64>
    //        byte 52,000,000       : weight blocks (bf16) -- dead after k_conv<64>
    //        [4*NEL, ...) bytes    : off output (fp32, final)
    //        [0, 4*NEL) bytes      : final out (fp32), written LAST by k_residual
    // d_ws:  [0, 2*NEL) bytes      : xt (bf16 D-innermost x) -- dead after k_deform
    //        [0, 4*NEL) bytes      : raw (conv2 output fp32 NCDHW) overwrites xt
    //        [4*NEL, +2KiB)        : st stats block
    float* out     = (float*)d_out;
    float* off_out = out + NEL;
    unsigned short* out1 = (unsigned short*)d_out;
    unsigned short* wb   = (unsigned short*)(out + 13000000);  // byte 52,000,000
    unsigned short* BtO  = wb;
    unsigned short* Bt1  = BtO + 27648;
    unsigned short* Bt2  = Bt1 + 110592;

    unsigned short* xt  = (unsigned short*)d_ws;
    float*          raw = (float*)d_ws;
    float*          st  = (float*)d_ws + NEL;   // bytes [4*NEL, 4*NEL+2048)
    // st: 0 sum1 | 64 sq1 | 128 sc1 | 192 sh1 | 256 sum2 | 320 sq2 | 384 sc2 | 448 sh2

    hipMemsetAsync(st, 0, 512 * sizeof(float), stream);

    k_transpose<<<dim3(16, 8, 7), 256, 0, stream>>>(x, xt);
    k_wprep<<<432, 256, 0, stream>>>(w_off, w1, w2, BtO, Bt1, Bt2);

    const dim3 cgrid(56, 16, 8);   // h, d, n (decoded via xcd_decode inside)
    k_conv<8, false, true><<<cgrid, 256, 0, stream>>>(xt, BtO, b_off, nullptr, nullptr, off_out);
    k_deform<<<cgrid, 512, 0, stream>>>(xt, off_out, Bt1, out1);

    k_stats_bf16<<<392, 256, 0, stream>>>(out1, st + 0, st + 64);
    k_finalize<<<1, 64, 0, stream>>>(st + 0, st + 64, g1, be1, st + 128, st + 192);

    k_conv<64, true, false><<<cgrid, 512, 0, stream>>>(out1, Bt2, b2, st + 128, st + 192, raw);

    k_stats<<<dim3(64, 8), 256, 0, stream>>>(raw, st + 256, st + 320);
    k_finalize<<<1, 64, 0, stream>>>(st + 256, st + 320, g2, be2, st + 384, st + 448);
    k_residual<<<25088, 256, 0, stream>>>((float4*)out, (const float4*)raw, (const float4*)x, st + 384, st + 448);
}

// Round 6
// 789.208 us; speedup vs baseline: 2.5879x; 1.0254x over previous
//
#include <hip/hip_runtime.h>

#define HW 3136
#define DHW 50176
#define NEL 25690112   // 8*64*16*56*56
#define CNT 401408.0f  // 8*16*56*56

typedef __attribute__((ext_vector_type(8))) short          short8;
typedef __attribute__((ext_vector_type(8))) unsigned short ushort8;
typedef __attribute__((ext_vector_type(4))) float          f32x4;

__device__ __forceinline__ unsigned f2bf(float f) {
    union { float f; unsigned u; } v; v.f = f;
    return (v.u + 0x7FFFu + ((v.u >> 16) & 1u)) >> 16;   // RNE
}
__device__ __forceinline__ float bf2f(unsigned u) {
    union { unsigned u; float f; } v; v.u = u << 16;
    return v.f;
}
// HW packed f32->bf16 RNE: 1 instr replaces ~10 VALU ops of 2x manual f2bf.
__device__ __forceinline__ unsigned cvt_pk_bf16(float lo, float hi) {
    unsigned r;
    asm("v_cvt_pk_bf16_f32 %0, %1, %2" : "=v"(r) : "v"(lo), "v"(hi));
    return r;
}

// XCD-aware swizzle for the 56x16x8 grids: XCD k (= bid % 8 round-robin)
// executes the contiguous logical range = ALL (h,d) of batch n=k, so each
// XCD's 4 MB L2 serves one n's xt/out1 slice (proven: FETCH 97->37 MB).
__device__ __forceinline__ void xcd_decode(int& h, int& d, int& n) {
    const int bid = blockIdx.x + 56 * (blockIdx.y + 16 * blockIdx.z);
    const int swz = (bid & 7) * 896 + (bid >> 3);
    h = swz % 56;
    const int dn = swz / 56;   // dn = d + 16*n, < 128
    d = dn & 15;
    n = dn >> 4;
}

// ---------------------------------------------------------------------------
// x (fp32 NCDHW) -> xt (bf16, D-innermost channels-last: [n][h*w][d][ci])
// ---------------------------------------------------------------------------
__global__ __launch_bounds__(256) void k_transpose(
    const float* __restrict__ x, unsigned short* __restrict__ xt)
{
    __shared__ unsigned lds[4][64 * 36];
    const int d = blockIdx.x, n = blockIdx.y, z = blockIdx.z;
    const int wave = threadIdx.x >> 6, lane = threadIdx.x & 63;
    const float* xb = x + (size_t)n * 64 * DHW + d * HW;
    unsigned short* xtb = xt + (size_t)n * DHW * 64;   // [hw][d][ci] inside
    unsigned* L = lds[wave];

    for (int c = z * 7 + wave; c < z * 7 + 7 && c < 49; c += 4) {
        const int P = c * 64;
#pragma unroll 4
        for (int cp = 0; cp < 32; ++cp) {
            const float a = xb[(size_t)(2 * cp) * DHW + P + lane];
            const float b = xb[(size_t)(2 * cp + 1) * DHW + P + lane];
            L[lane * 36 + cp] = cvt_pk_bf16(a, b);
        }
#pragma unroll
        for (int k = 0; k < 8; ++k) {
            const int r = (lane >> 3) + 8 * k;          // pixel within 64-chunk
            const uint4 v = *(const uint4*)&L[r * 36 + 4 * (lane & 7)];
            *(uint4*)((char*)xtb + ((size_t)(P + r) * 16 + d) * 128 + (lane & 7) * 16) = v;
        }
    }
}

// ---------------------------------------------------------------------------
// Weight prep -- LANE-MAJOR PACKED fragment layout so each per-tap B load is
// one fully-coalesced 1 KB wave read (8 dense lines vs 16 half lines):
//   BtO[tap][ks][lane]{short8}           : 27*2*512 shorts
//   Bt1/Bt2[tap][rg][ks][lane]{short8}   : 27*4*2*512 shorts
// lane l of the load maps to row rg*16+(l&15), ci = ks*32+(l>>4)*8+e.
// ---------------------------------------------------------------------------
__global__ __launch_bounds__(256) void k_wprep(
    const float* __restrict__ w_off, const float* __restrict__ w1,
    const float* __restrict__ w2, unsigned short* __restrict__ BtO,
    unsigned short* __restrict__ Bt1, unsigned short* __restrict__ Bt2)
{
    const int i = blockIdx.x * 256 + threadIdx.x;
    if (i < 27648) {
        const int tap = i / 1024, r = i - tap * 1024;
        const int ks = r >> 9, r3 = r & 511, lane = r3 >> 3, e = r3 & 7;
        const int row = lane & 15;
        const int ci  = ks * 32 + (lane >> 4) * 8 + e;
        BtO[i] = (row < 8) ? (unsigned short)f2bf(w_off[(row * 64 + ci) * 27 + tap]) : 0;
    }
    if (i < 110592) {
        const int tap = i / 4096, r = i - tap * 4096;
        const int rg = r >> 10, r2 = r & 1023;
        const int ks = r2 >> 9, r3 = r2 & 511, lane = r3 >> 3, e = r3 & 7;
        const int co = rg * 16 + (lane & 15);
        const int ci = ks * 32 + (lane >> 4) * 8 + e;
        Bt1[i] = (unsigned short)f2bf(w1[(co * 64 + ci) * 27 + tap]);
        Bt2[i] = (unsigned short)f2bf(w2[(co * 64 + ci) * 27 + tap]);
    }
}

// ---------------------------------------------------------------------------
// Standard 3x3x3 conv via MFMA, LDS-staged. Block = (h, d, n).
// A-tile: 9 rows (3 dq x 3 hq) x 58 px x 64 ci bf16, row stride 72 shorts.
// NCO==8 : 256 thr, 4 waves x (1 mf x 1 nf).
// NCO==64: 512 thr, 8 waves x (2 mf x 1 nf).
// ---------------------------------------------------------------------------
template<int NCO, bool BN, bool DIN>
__global__ __launch_bounds__((NCO == 8) ? 256 : 512) void k_conv(
    const unsigned short* __restrict__ src, const unsigned short* __restrict__ Bt,
    const float* __restrict__ bias, const float* __restrict__ scv,
    const float* __restrict__ shv, float* __restrict__ dst)
{
    constexpr int NT = (NCO == 8) ? 256 : 512;
    __shared__ unsigned short A[538 * 72];   // 9*58=522 slots + 16 overrun pad
    int h, d, n;
    xcd_decode(h, d, n);
    const int tid = threadIdx.x;
    const int wave = tid >> 6, lane = tid & 63, lm = lane & 15, quad = lane >> 4;
    const int k8 = tid & 7;                  // fixed ci-chunk per thread

    float scr[8], shr[8];
    if constexpr (BN) {
#pragma unroll
        for (int e = 0; e < 8; ++e) { scr[e] = scv[k8 * 8 + e]; shr[e] = shv[k8 * 8 + e]; }
    }

    const unsigned short* snb = DIN ? (src + (size_t)n * DHW * 64)
                                    : (src + (size_t)(n * 16) * HW * 64);

    // ---- stage 4176 16B chunks ----
    for (int c = tid; c < 4176; c += NT) {
        const int idx = c >> 3;
        const int row = idx / 58, px = idx - row * 58;
        const int kd = row / 3, kh = row - kd * 3;
        const int dq = d + kd - 1, hq = h + kh - 1, wq = px - 1;
        uint4 pk = {0u, 0u, 0u, 0u};
        if (((unsigned)dq < 16u) & ((unsigned)hq < 56u) & ((unsigned)wq < 56u)) {
            const size_t off = DIN ? (((size_t)(hq * 56 + wq) * 16 + dq) * 64)
                                   : (((size_t)dq * HW + hq * 56 + wq) * 64);
            const ushort8 val = *(const ushort8*)(snb + off + k8 * 8);
            if constexpr (BN) {
                float f[8];
#pragma unroll
                for (int e = 0; e < 8; ++e)
                    f[e] = fmaxf(fmaf(bf2f(val[e]), scr[e], shr[e]), 0.f);
                pk.x = cvt_pk_bf16(f[0], f[1]);
                pk.y = cvt_pk_bf16(f[2], f[3]);
                pk.z = cvt_pk_bf16(f[4], f[5]);
                pk.w = cvt_pk_bf16(f[6], f[7]);
            } else {
                pk = *(const uint4*)&val;
            }
        }
        *(uint4*)&A[(size_t)idx * 72 + k8 * 8] = pk;
    }
    __syncthreads();

    constexpr int NFm = (NCO == 8) ? 1 : 2;
    const int mf0 = (NCO == 8) ? wave : (wave & 1) * 2;
    const int nf0 = (NCO == 8) ? 0 : (wave >> 1);        // 0..3 (single n-frag)

    f32x4 acc[NFm];
#pragma unroll
    for (int i = 0; i < NFm; ++i) acc[i] = (f32x4){0.f, 0.f, 0.f, 0.f};

    // packed-B address for (tap, ks)
    auto bofs = [&](int t, int ks) -> size_t {
        if constexpr (NCO == 8)
            return ((size_t)t * 2 + ks) * 512 + lane * 8;
        else
            return (((size_t)t * 4 + nf0) * 2 + ks) * 512 + lane * 8;
    };

    // ---- 27-tap K-loop, B software-pipelined ----
    short8 bc[2];
#pragma unroll
    for (int ks = 0; ks < 2; ++ks) bc[ks] = *(const short8*)(Bt + bofs(0, ks));

#pragma unroll 1
    for (int t = 0; t < 27; ++t) {
        short8 bnx[2];
        if (t < 26) {
#pragma unroll
            for (int ks = 0; ks < 2; ++ks) bnx[ks] = *(const short8*)(Bt + bofs(t + 1, ks));
        }
        const int kd = t / 9, r9 = t - kd * 9, kh = r9 / 3, kw = r9 - kh * 3;
        const int rowb = (kd * 3 + kh) * 58 + kw;
        short8 a[2][NFm];
#pragma unroll
        for (int ks = 0; ks < 2; ++ks)
#pragma unroll
            for (int mf = 0; mf < NFm; ++mf)
                a[ks][mf] = *(const short8*)&A[(size_t)(rowb + (mf0 + mf) * 16 + lm) * 72 + ks * 32 + quad * 8];
#pragma unroll
        for (int ks = 0; ks < 2; ++ks)
#pragma unroll
            for (int mf = 0; mf < NFm; ++mf)
                acc[mf] = __builtin_amdgcn_mfma_f32_16x16x32_bf16(a[ks][mf], bc[ks], acc[mf], 0, 0, 0);
        if (t < 26) {
#pragma unroll
            for (int ks = 0; ks < 2; ++ks) bc[ks] = bnx[ks];
        }
    }

    // ---- epilogue: LDS transpose -> fp32 NCDHW + bias ----
    __syncthreads();
    float* E = (float*)A;
    constexpr int CSTR = (NCO == 64) ? 65 : 17;
#pragma unroll
    for (int mf = 0; mf < NFm; ++mf)
#pragma unroll
        for (int r = 0; r < 4; ++r) {
            const int mm = (mf0 + mf) * 16 + quad * 4 + r;
            if (mm < 56) E[mm * CSTR + nf0 * 16 + lm] = acc[mf][r];
        }
    __syncthreads();
    for (int f = tid; f < 56 * NCO; f += NT) {
        const int co = f / 56, w0 = f - co * 56;
        dst[((size_t)(n * NCO + co) * 16 + d) * HW + h * 56 + w0] = E[w0 * CSTR + co] + bias[co];
    }
}

// ---------------------------------------------------------------------------
// Temporal deformable conv. 512 thr, 8 waves x (2 mf x 1 nf).
// Staging BUILDS the interpolated field: row (kd, hq) holds
// g_kd[n, :, d, hq, :] at pos = off(d,hq,wq)+d+kd-1.
// Task order g-MINOR: the 8 lanes of one pixel read the 8 chunks of the
// SAME 128-B line (dense gather). Output: bf16 ch-last [pixel][co].
// ---------------------------------------------------------------------------
__global__ __launch_bounds__(512) void k_deform(
    const unsigned short* __restrict__ xt, const float* __restrict__ offo,
    const unsigned short* __restrict__ Bt, unsigned short* __restrict__ out1)
{
    __shared__ unsigned short A[538 * 72];
    int h, d, n;
    xcd_decode(h, d, n);
    const int tid = threadIdx.x;
    const int wave = tid >> 6, lane = tid & 63, lm = lane & 15, quad = lane >> 4;

    // ---- prefetch the 3 offset values this thread needs (g-minor decode) ----
    float pv[3];
#pragma unroll
    for (int it = 0; it < 3; ++it) {
        const int c = tid + it * 512;
        float p = 0.f;
        if (c < 1392) {
            const int g = c & 7, pix = c >> 3;           // pix < 174
            const int hq3 = pix / 58, px = pix - hq3 * 58;
            const int habs = h + hq3 - 1, wq = px - 1;
            if (((unsigned)habs < 56u) & ((unsigned)wq < 56u))
                p = offo[((size_t)(n * 8 + g) * 16 + d) * HW + habs * 56 + wq] + (float)d;
        }
        pv[it] = p;
    }

    // ---- gather + lerp staging: 1392 tasks (174 px x 8 g), g-minor ----
#pragma unroll
    for (int it = 0; it < 3; ++it) {
        const int c = tid + it * 512;
        if (c >= 1392) break;
        const int g = c & 7, pix = c >> 3;
        const int hq3 = pix / 58, px = pix - hq3 * 58;
        const int habs = h + hq3 - 1, wq = px - 1;
        uint4 p0 = {0u,0u,0u,0u}, p1 = {0u,0u,0u,0u}, p2 = {0u,0u,0u,0u};
        if (((unsigned)habs < 56u) & ((unsigned)wq < 56u)) {
            const float p = pv[it];
            const float fl = floorf(p);
            const float fr = p - fl;
            const int i0 = (int)fl;
            // D-innermost: plane stride is 64 shorts (128 B); 8 g-lanes of one
            // pixel read the 8 consecutive 16-B chunks of each plane line.
            const unsigned short* cb = xt + ((size_t)n * HW + habs * 56 + wq) * (16 * 64) + g * 8;
            float s[4][8];
#pragma unroll
            for (int j = 0; j < 4; ++j) {
                const int dj = i0 - 1 + j;
                const bool ok = (unsigned)dj < 16u;
                const ushort8 v = *(const ushort8*)(cb + (size_t)(ok ? dj : 0) * 64);
#pragma unroll
                for (int e = 0; e < 8; ++e) s[j][e] = ok ? bf2f(v[e]) : 0.f;
            }
            float a0[8], a1[8], a2[8];
#pragma unroll
            for (int e = 0; e < 8; ++e) {
                a0[e] = fmaf(fr, s[1][e] - s[0][e], s[0][e]);
                a1[e] = fmaf(fr, s[2][e] - s[1][e], s[1][e]);
                a2[e] = fmaf(fr, s[3][e] - s[2][e], s[2][e]);
            }
            p0.x = cvt_pk_bf16(a0[0], a0[1]); p0.y = cvt_pk_bf16(a0[2], a0[3]);
            p0.z = cvt_pk_bf16(a0[4], a0[5]); p0.w = cvt_pk_bf16(a0[6], a0[7]);
            p1.x = cvt_pk_bf16(a1[0], a1[1]); p1.y = cvt_pk_bf16(a1[2], a1[3]);
            p1.z = cvt_pk_bf16(a1[4], a1[5]); p1.w = cvt_pk_bf16(a1[6], a1[7]);
            p2.x = cvt_pk_bf16(a2[0], a2[1]); p2.y = cvt_pk_bf16(a2[2], a2[3]);
            p2.z = cvt_pk_bf16(a2[4], a2[5]); p2.w = cvt_pk_bf16(a2[6], a2[7]);
        }
        const int sl = hq3 * 58 + px;
        *(uint4*)&A[(size_t)(sl          ) * 72 + g * 8] = p0;   // kd=0 rows 0..2
        *(uint4*)&A[(size_t)(sl + 3 * 58 ) * 72 + g * 8] = p1;   // kd=1 rows 3..5
        *(uint4*)&A[(size_t)(sl + 6 * 58 ) * 72 + g * 8] = p2;   // kd=2 rows 6..8
    }
    __syncthreads();

    const int mf0 = (wave & 1) * 2, nf0 = wave >> 1;     // 2 mf x 1 nf per wave
    f32x4 acc[2];
    acc[0] = (f32x4){0.f, 0.f, 0.f, 0.f};
    acc[1] = (f32x4){0.f, 0.f, 0.f, 0.f};

    short8 bc[2];
#pragma unroll
    for (int ks = 0; ks < 2; ++ks)
        bc[ks] = *(const short8*)(Bt + (((size_t)0 * 4 + nf0) * 2 + ks) * 512 + lane * 8);

#pragma unroll 1
    for (int t = 0; t < 27; ++t) {
        short8 bnx[2];
        if (t < 26) {
#pragma unroll
            for (int ks = 0; ks < 2; ++ks)
                bnx[ks] = *(const short8*)(Bt + (((size_t)(t + 1) * 4 + nf0) * 2 + ks) * 512 + lane * 8);
        }
        const int kd = t / 9, r9 = t - kd * 9, kh = r9 / 3, kw = r9 - kh * 3;
        const int rowb = (kd * 3 + kh) * 58 + kw;
        short8 a[2][2];
#pragma unroll
        for (int ks = 0; ks < 2; ++ks)
#pragma unroll
            for (int mf = 0; mf < 2; ++mf)
                a[ks][mf] = *(const short8*)&A[(size_t)(rowb + (mf0 + mf) * 16 + lm) * 72 + ks * 32 + quad * 8];
#pragma unroll
        for (int ks = 0; ks < 2; ++ks)
#pragma unroll
            for (int mf = 0; mf < 2; ++mf)
                acc[mf] = __builtin_amdgcn_mfma_f32_16x16x32_bf16(a[ks][mf], bc[ks], acc[mf], 0, 0, 0);
        if (t < 26) {
#pragma unroll
            for (int ks = 0; ks < 2; ++ks) bc[ks] = bnx[ks];
        }
    }

    // ---- epilogue: bf16 tile in LDS -> coalesced ch-last stores ----
    __syncthreads();
#pragma unroll
    for (int mf = 0; mf < 2; ++mf)
#pragma unroll
        for (int r = 0; r < 4; ++r) {
            const int mm = (mf0 + mf) * 16 + quad * 4 + r;
            if (mm < 56)
                A[mm * 72 + nf0 * 16 + lm] = (unsigned short)f2bf(acc[mf][r]);
        }
    __syncthreads();
    const size_t pixb = ((size_t)(n * 16) + d) * HW + h * 56;
    if (tid < 448) {
        const int px = tid >> 3, kk = tid & 7;
        *(uint4*)(out1 + (pixb + px) * 64 + kk * 8) = *(const uint4*)&A[px * 72 + kk * 8];
    }
}

// ---------------- per-channel stats over bf16 ch-last ----------------------
__global__ __launch_bounds__(256) void k_stats_bf16(
    const unsigned short* __restrict__ src, float* __restrict__ sums, float* __restrict__ sqs)
{
    const int c4 = threadIdx.x & 15, part = threadIdx.x >> 4;   // 16 ci-quads, 16 parts
    const size_t base = (size_t)blockIdx.x * 1024;
    float s[4] = {0.f, 0.f, 0.f, 0.f}, q[4] = {0.f, 0.f, 0.f, 0.f};
#pragma unroll 4
    for (int i = 0; i < 64; ++i) {
        const size_t pix = base + part + (size_t)i * 16;
        const uint2 v = *(const uint2*)(src + pix * 64 + c4 * 4);
        const float f0 = bf2f(v.x & 0xffffu), f1 = bf2f(v.x >> 16);
        const float f2 = bf2f(v.y & 0xffffu), f3 = bf2f(v.y >> 16);
        s[0] += f0; q[0] = fmaf(f0, f0, q[0]);
        s[1] += f1; q[1] = fmaf(f1, f1, q[1]);
        s[2] += f2; q[2] = fmaf(f2, f2, q[2]);
        s[3] += f3; q[3] = fmaf(f3, f3, q[3]);
    }
    __shared__ float S[64], Q[64];
    if (threadIdx.x < 64) { S[threadIdx.x] = 0.f; Q[threadIdx.x] = 0.f; }
    __syncthreads();
#pragma unroll
    for (int e = 0; e < 4; ++e) {
        atomicAdd(&S[c4 * 4 + e], s[e]);
        atomicAdd(&Q[c4 * 4 + e], q[e]);
    }
    __syncthreads();
    if (threadIdx.x < 64) {
        atomicAdd(&sums[threadIdx.x], S[threadIdx.x]);
        atomicAdd(&sqs[threadIdx.x],  Q[threadIdx.x]);
    }
}

// ---------------- per-channel stats, NCDHW fp32 ----------------------------
__global__ __launch_bounds__(256) void k_stats(
    const float* __restrict__ src, float* __restrict__ sums, float* __restrict__ sqs)
{
    const int c = blockIdx.x, n = blockIdx.y;
    const float* p = src + ((size_t)n * 64 + c) * DHW;
    float s = 0.f, q = 0.f;
    for (int i = threadIdx.x; i < DHW; i += 256) {
        const float v = p[i];
        s += v; q = fmaf(v, v, q);
    }
    for (int o = 32; o > 0; o >>= 1) {
        s += __shfl_down(s, o);
        q += __shfl_down(q, o);
    }
    __shared__ float ls[4], lq[4];
    const int wv = threadIdx.x >> 6, lane = threadIdx.x & 63;
    if (lane == 0) { ls[wv] = s; lq[wv] = q; }
    __syncthreads();
    if (threadIdx.x == 0) {
        atomicAdd(&sums[c], ls[0] + ls[1] + ls[2] + ls[3]);
        atomicAdd(&sqs[c],  lq[0] + lq[1] + lq[2] + lq[3]);
    }
}

// ---------------- finalize BN: scale/shift ---------------------------------
__global__ void k_finalize(const float* __restrict__ sums, const float* __restrict__ sqs,
                           const float* __restrict__ gamma, const float* __restrict__ beta,
                           float* __restrict__ scale, float* __restrict__ shift)
{
    const int c = threadIdx.x; // 64 threads
    const float mean = sums[c] / CNT;
    const float var  = sqs[c] / CNT - mean * mean;
    const float sc   = gamma[c] * rsqrtf(var + 1e-5f);
    scale[c] = sc;
    shift[c] = fmaf(-mean, sc, beta[c]);
}

// -------- BN2 + residual + ReLU: dst = relu(bn(raw) + x)  (float4) ---------
__global__ __launch_bounds__(256) void k_residual(
    float4* __restrict__ dst, const float4* __restrict__ raw,
    const float4* __restrict__ x,
    const float* __restrict__ scale, const float* __restrict__ shift)
{
    const int i = blockIdx.x * 256 + threadIdx.x;   // < 6422528
    const int c = (i / 12544) & 63;                  // wave-uniform
    const float sc = scale[c], sh = shift[c];
    float4 v = raw[i];
    const float4 xv = x[i];
    v.x = fmaxf(fmaf(v.x, sc, sh) + xv.x, 0.f);
    v.y = fmaxf(fmaf(v.y, sc, sh) + xv.y, 0.f);
    v.z = fmaxf(fmaf(v.z, sc, sh) + xv.z, 0.f);
    v.w = fmaxf(fmaf(v.w, sc, sh) + xv.w, 0.f);
    dst[i] = v;
}

extern "C" void kernel_launch(void* const* d_in, const int* in_sizes, int n_in,
                              void* d_out, int out_size, void* d_ws, size_t ws_size,
                              hipStream_t stream) {
    const float* x     = (const float*)d_in[0];
    const float* w_off = (const float*)d_in[1];
    const float* b_off = (const float*)d_in[2];
    const float* w1    = (const float*)d_in[3];
    const float* w2    = (const float*)d_in[4];
    const float* b2    = (const float*)d_in[5];
    const float* g1    = (const float*)d_in[6];
    const float* be1   = (const float*)d_in[7];
    const float* g2    = (const float*)d_in[8];
    const float* be2   = (const float*)d_in[9];

    // ---- buffer plan ----
    // d_out: [0, 2*NEL) bytes      : out1 (deform result, bf16 ch-last) -- dead after k_conv<64>
    //        byte 52,000,000       : weight blocks (bf16) -- dead after k_conv<64>
    //        [4*NEL, ...) bytes    : off output (fp32, final)
    //        [0, 4*NEL) bytes      : final out (fp32), written LAST by k_residual
    // d_ws:  [0, 2*NEL) bytes      : xt (bf16 D-innermost x) -- dead after k_deform
    //        [0, 4*NEL) bytes      : raw (conv2 output fp32 NCDHW) overwrites xt
    //        [4*NEL, +2KiB)        : st stats block
    float* out     = (float*)d_out;
    float* off_out = out + NEL;
    unsigned short* out1 = (unsigned short*)d_out;
    unsigned short* wb   = (unsigned short*)(out + 13000000);  // byte 52,000,000
    unsigned short* BtO  = wb;
    unsigned short* Bt1  = BtO + 27648;
    unsigned short* Bt2  = Bt1 + 110592;

    unsigned short* xt  = (unsigned short*)d_ws;
    float*          raw = (float*)d_ws;
    float*          st  = (float*)d_ws + NEL;   // bytes [4*NEL, 4*NEL+2048)
    // st: 0 sum1 | 64 sq1 | 128 sc1 | 192 sh1 | 256 sum2 | 320 sq2 | 384 sc2 | 448 sh2

    hipMemsetAsync(st, 0, 512 * sizeof(float), stream);

    k_transpose<<<dim3(16, 8, 7), 256, 0, stream>>>(x, xt);
    k_wprep<<<432, 256, 0, stream>>>(w_off, w1, w2, BtO, Bt1, Bt2);

    const dim3 cgrid(56, 16, 8);   // h, d, n (decoded via xcd_decode inside)
    k_conv<8, false, true><<<cgrid, 256, 0, stream>>>(xt, BtO, b_off, nullptr, nullptr, off_out);
    k_deform<<<cgrid, 512, 0, stream>>>(xt, off_out, Bt1, out1);

    k_stats_bf16<<<392, 256, 0, stream>>>(out1, st + 0, st + 64);
    k_finalize<<<1, 64, 0, stream>>>(st + 0, st + 64, g1, be1, st + 128, st + 192);

    k_conv<64, true, false><<<cgrid, 512, 0, stream>>>(out1, Bt2, b2, st + 128, st + 192, raw);

    k_stats<<<dim3(64, 8), 256, 0, stream>>>(raw, st + 256, st + 320);
    k_finalize<<<1, 64, 0, stream>>>(st + 256, st + 320, g2, be2, st + 384, st + 448);
    k_residual<<<25088, 256, 0, stream>>>((float4*)out, (const float4*)raw, (const float4*)x, st + 384, st + 448);
}

// Round 7
// 751.913 us; speedup vs baseline: 2.7163x; 1.0496x over previous
//
#include <hip/hip_runtime.h>

#define HW 3136
#define DHW 50176
#define NEL 25690112   // 8*64*16*56*56
#define CNT 401408.0f  // 8*16*56*56

typedef __attribute__((ext_vector_type(8))) short          short8;
typedef __attribute__((ext_vector_type(8))) unsigned short ushort8;
typedef __attribute__((ext_vector_type(4))) float          f32x4;

__device__ __forceinline__ unsigned f2bf(float f) {
    union { float f; unsigned u; } v; v.f = f;
    return (v.u + 0x7FFFu + ((v.u >> 16) & 1u)) >> 16;   // RNE
}
__device__ __forceinline__ float bf2f(unsigned u) {
    union { unsigned u; float f; } v; v.u = u << 16;
    return v.f;
}
// HW packed f32->bf16 RNE: 1 instr replaces ~10 VALU ops of 2x manual f2bf.
__device__ __forceinline__ unsigned cvt_pk_bf16(float lo, float hi) {
    unsigned r;
    asm("v_cvt_pk_bf16_f32 %0, %1, %2" : "=v"(r) : "v"(lo), "v"(hi));
    return r;
}

// XCD-aware swizzle for the 56x16x8 grids: XCD k (= bid % 8 round-robin)
// executes the contiguous logical range = ALL (h,d) of batch n=k, so each
// XCD's 4 MB L2 serves one n's xt/out1 slice (proven: FETCH 97->37 MB).
__device__ __forceinline__ void xcd_decode(int& h, int& d, int& n) {
    const int bid = blockIdx.x + 56 * (blockIdx.y + 16 * blockIdx.z);
    const int swz = (bid & 7) * 896 + (bid >> 3);
    h = swz % 56;
    const int dn = swz / 56;   // dn = d + 16*n, < 128
    d = dn & 15;
    n = dn >> 4;
}

// ---------------------------------------------------------------------------
// x (fp32 NCDHW) -> xt (bf16, D-innermost channels-last: [n][h*w][d][ci])
// ---------------------------------------------------------------------------
__global__ __launch_bounds__(256) void k_transpose(
    const float* __restrict__ x, unsigned short* __restrict__ xt)
{
    __shared__ unsigned lds[4][64 * 36];
    const int d = blockIdx.x, n = blockIdx.y, z = blockIdx.z;
    const int wave = threadIdx.x >> 6, lane = threadIdx.x & 63;
    const float* xb = x + (size_t)n * 64 * DHW + d * HW;
    unsigned short* xtb = xt + (size_t)n * DHW * 64;   // [hw][d][ci] inside
    unsigned* L = lds[wave];

    for (int c = z * 7 + wave; c < z * 7 + 7 && c < 49; c += 4) {
        const int P = c * 64;
#pragma unroll 4
        for (int cp = 0; cp < 32; ++cp) {
            const float a = xb[(size_t)(2 * cp) * DHW + P + lane];
            const float b = xb[(size_t)(2 * cp + 1) * DHW + P + lane];
            L[lane * 36 + cp] = cvt_pk_bf16(a, b);
        }
#pragma unroll
        for (int k = 0; k < 8; ++k) {
            const int r = (lane >> 3) + 8 * k;          // pixel within 64-chunk
            const uint4 v = *(const uint4*)&L[r * 36 + 4 * (lane & 7)];
            *(uint4*)((char*)xtb + ((size_t)(P + r) * 16 + d) * 128 + (lane & 7) * 16) = v;
        }
    }
}

// ---------------------------------------------------------------------------
// Weight prep -- LANE-MAJOR PACKED fragment layout so each per-tap B load is
// one fully-coalesced 1 KB wave read (8 dense lines vs 16 half lines):
//   BtO[tap][ks][lane]{short8}           : 27*2*512 shorts
//   Bt1/Bt2[tap][rg][ks][lane]{short8}   : 27*4*2*512 shorts
// lane l of the load maps to row rg*16+(l&15), ci = ks*32+(l>>4)*8+e.
// ---------------------------------------------------------------------------
__global__ __launch_bounds__(256) void k_wprep(
    const float* __restrict__ w_off, const float* __restrict__ w1,
    const float* __restrict__ w2, unsigned short* __restrict__ BtO,
    unsigned short* __restrict__ Bt1, unsigned short* __restrict__ Bt2)
{
    const int i = blockIdx.x * 256 + threadIdx.x;
    if (i < 27648) {
        const int tap = i / 1024, r = i - tap * 1024;
        const int ks = r >> 9, r3 = r & 511, lane = r3 >> 3, e = r3 & 7;
        const int row = lane & 15;
        const int ci  = ks * 32 + (lane >> 4) * 8 + e;
        BtO[i] = (row < 8) ? (unsigned short)f2bf(w_off[(row * 64 + ci) * 27 + tap]) : 0;
    }
    if (i < 110592) {
        const int tap = i / 4096, r = i - tap * 4096;
        const int rg = r >> 10, r2 = r & 1023;
        const int ks = r2 >> 9, r3 = r2 & 511, lane = r3 >> 3, e = r3 & 7;
        const int co = rg * 16 + (lane & 15);
        const int ci = ks * 32 + (lane >> 4) * 8 + e;
        Bt1[i] = (unsigned short)f2bf(w1[(co * 64 + ci) * 27 + tap]);
        Bt2[i] = (unsigned short)f2bf(w2[(co * 64 + ci) * 27 + tap]);
    }
}

// ---------------------------------------------------------------------------
// Standard 3x3x3 conv via MFMA, LDS-staged. Block = (h, d, n).
// A-tile: 9 rows (3 dq x 3 hq) x 58 px x 64 ci bf16, row stride 72 shorts.
// NCO==8 : 256 thr, 4 waves x (1 mf x 1 nf).
// NCO==64: 512 thr, 8 waves x (2 mf x 1 nf).
// K-loop is strength-reduced: r9-outer/kw-unrolled, incremental LDS row
// offset and incremental 32-bit B offset (no per-tap divides / muls).
// ---------------------------------------------------------------------------
template<int NCO, bool BN, bool DIN>
__global__ __launch_bounds__((NCO == 8) ? 256 : 512) void k_conv(
    const unsigned short* __restrict__ src, const unsigned short* __restrict__ Bt,
    const float* __restrict__ bias, const float* __restrict__ scv,
    const float* __restrict__ shv, float* __restrict__ dst)
{
    constexpr int NT = (NCO == 8) ? 256 : 512;
    __shared__ unsigned short A[538 * 72];   // 9*58=522 slots + 16 overrun pad
    int h, d, n;
    xcd_decode(h, d, n);
    const int tid = threadIdx.x;
    const int wave = tid >> 6, lane = tid & 63, lm = lane & 15, quad = lane >> 4;
    const int k8 = tid & 7;                  // fixed ci-chunk per thread

    float scr[8], shr[8];
    if constexpr (BN) {
#pragma unroll
        for (int e = 0; e < 8; ++e) { scr[e] = scv[k8 * 8 + e]; shr[e] = shv[k8 * 8 + e]; }
    }

    const unsigned short* snb = DIN ? (src + (size_t)n * DHW * 64)
                                    : (src + (size_t)(n * 16) * HW * 64);

    // ---- stage 4176 16B chunks ----
    for (int c = tid; c < 4176; c += NT) {
        const int idx = c >> 3;
        const int row = idx / 58, px = idx - row * 58;
        const int kd = row / 3, kh = row - kd * 3;
        const int dq = d + kd - 1, hq = h + kh - 1, wq = px - 1;
        uint4 pk = {0u, 0u, 0u, 0u};
        if (((unsigned)dq < 16u) & ((unsigned)hq < 56u) & ((unsigned)wq < 56u)) {
            const size_t off = DIN ? (((size_t)(hq * 56 + wq) * 16 + dq) * 64)
                                   : (((size_t)dq * HW + hq * 56 + wq) * 64);
            const ushort8 val = *(const ushort8*)(snb + off + k8 * 8);
            if constexpr (BN) {
                float f[8];
#pragma unroll
                for (int e = 0; e < 8; ++e)
                    f[e] = fmaxf(fmaf(bf2f(val[e]), scr[e], shr[e]), 0.f);
                pk.x = cvt_pk_bf16(f[0], f[1]);
                pk.y = cvt_pk_bf16(f[2], f[3]);
                pk.z = cvt_pk_bf16(f[4], f[5]);
                pk.w = cvt_pk_bf16(f[6], f[7]);
            } else {
                pk = *(const uint4*)&val;
            }
        }
        *(uint4*)&A[(size_t)idx * 72 + k8 * 8] = pk;
    }
    __syncthreads();

    constexpr int NFm = (NCO == 8) ? 1 : 2;
    const int mf0 = (NCO == 8) ? wave : (wave & 1) * 2;
    const int nf0 = (NCO == 8) ? 0 : (wave >> 1);        // 0..3 (single n-frag)

    f32x4 acc[NFm];
#pragma unroll
    for (int i = 0; i < NFm; ++i) acc[i] = (f32x4){0.f, 0.f, 0.f, 0.f};

    // ---- 27-tap K-loop, strength-reduced, B software-pipelined ----
    constexpr unsigned BSTR = (NCO == 8) ? 1024u : 4096u;    // shorts per tap
    const unsigned short* Btb = (NCO == 8) ? Bt : (Bt + (unsigned)nf0 * 1024);
    unsigned boff = (unsigned)lane * 8;                       // tap-0 fragment
    short8 bc0 = *(const short8*)(Btb + boff);
    short8 bc1 = *(const short8*)(Btb + boff + 512);
    boff += BSTR;
    unsigned arow = (unsigned)(mf0 * 16 + lm) * 72 + quad * 8;  // A base (shorts)

#pragma unroll 1
    for (int r9 = 0; r9 < 9; ++r9) {
#pragma unroll
        for (int kw = 0; kw < 3; ++kw) {
            const bool more = (kw < 2) | (r9 < 8);            // t < 26
            short8 bn0, bn1;
            if (more) {
                bn0 = *(const short8*)(Btb + boff);
                bn1 = *(const short8*)(Btb + boff + 512);
            }
            const unsigned ab = arow + kw * 72;
            short8 a0[NFm], a1[NFm];
#pragma unroll
            for (int mf = 0; mf < NFm; ++mf) {
                a0[mf] = *(const short8*)&A[ab + mf * 1152];
                a1[mf] = *(const short8*)&A[ab + mf * 1152 + 32];
            }
#pragma unroll
            for (int mf = 0; mf < NFm; ++mf)
                acc[mf] = __builtin_amdgcn_mfma_f32_16x16x32_bf16(a0[mf], bc0, acc[mf], 0, 0, 0);
#pragma unroll
            for (int mf = 0; mf < NFm; ++mf)
                acc[mf] = __builtin_amdgcn_mfma_f32_16x16x32_bf16(a1[mf], bc1, acc[mf], 0, 0, 0);
            if (more) {
                bc0 = bn0; bc1 = bn1;
                boff += BSTR;
            }
        }
        arow += 58 * 72;
    }

    // ---- epilogue: LDS transpose -> fp32 NCDHW + bias ----
    __syncthreads();
    float* E = (float*)A;
    constexpr int CSTR = (NCO == 64) ? 65 : 17;
#pragma unroll
    for (int mf = 0; mf < NFm; ++mf)
#pragma unroll
        for (int r = 0; r < 4; ++r) {
            const int mm = (mf0 + mf) * 16 + quad * 4 + r;
            if (mm < 56) E[mm * CSTR + nf0 * 16 + lm] = acc[mf][r];
        }
    __syncthreads();
    for (int f = tid; f < 56 * NCO; f += NT) {
        const int co = f / 56, w0 = f - co * 56;
        dst[((size_t)(n * NCO + co) * 16 + d) * HW + h * 56 + w0] = E[w0 * CSTR + co] + bias[co];
    }
}

// ---------------------------------------------------------------------------
// Temporal deformable conv. 512 thr, 8 waves x (2 mf x 1 nf).
// Staging BUILDS the interpolated field: row (kd, hq) holds
// g_kd[n, :, d, hq, :] at pos = off(d,hq,wq)+d+kd-1.
// Task order g-MINOR (dense 128-B gathers); OOB masks folded into the SIX
// scalar lerp coefficients (no per-element cndmask). Output: bf16 ch-last.
// ---------------------------------------------------------------------------
__global__ __launch_bounds__(512) void k_deform(
    const unsigned short* __restrict__ xt, const float* __restrict__ offo,
    const unsigned short* __restrict__ Bt, unsigned short* __restrict__ out1)
{
    __shared__ unsigned short A[538 * 72];
    int h, d, n;
    xcd_decode(h, d, n);
    const int tid = threadIdx.x;
    const int wave = tid >> 6, lane = tid & 63, lm = lane & 15, quad = lane >> 4;

    // ---- prefetch the 3 offset values this thread needs (g-minor decode) ----
    float pv[3];
#pragma unroll
    for (int it = 0; it < 3; ++it) {
        const int c = tid + it * 512;
        float p = 0.f;
        if (c < 1392) {
            const int g = c & 7, pix = c >> 3;           // pix < 174
            const int hq3 = pix / 58, px = pix - hq3 * 58;
            const int habs = h + hq3 - 1, wq = px - 1;
            if (((unsigned)habs < 56u) & ((unsigned)wq < 56u))
                p = offo[((size_t)(n * 8 + g) * 16 + d) * HW + habs * 56 + wq] + (float)d;
        }
        pv[it] = p;
    }

    // ---- gather + lerp staging: 1392 tasks (174 px x 8 g), g-minor ----
#pragma unroll
    for (int it = 0; it < 3; ++it) {
        const int c = tid + it * 512;
        if (c >= 1392) break;
        const int g = c & 7, pix = c >> 3;
        const int hq3 = pix / 58, px = pix - hq3 * 58;
        const int habs = h + hq3 - 1, wq = px - 1;
        uint4 p0 = {0u,0u,0u,0u}, p1 = {0u,0u,0u,0u}, p2 = {0u,0u,0u,0u};
        if (((unsigned)habs < 56u) & ((unsigned)wq < 56u)) {
            const float p = pv[it];
            const float fl = floorf(p);
            const float fr = p - fl;
            const int i0 = (int)fl;
            // D-innermost: plane stride is 64 shorts (128 B); 8 g-lanes of one
            // pixel read the 8 consecutive 16-B chunks of each plane line.
            const unsigned short* cb = xt + ((size_t)n * HW + habs * 56 + wq) * (16 * 64) + g * 8;
            float sv[4][8], m[4];
#pragma unroll
            for (int j = 0; j < 4; ++j) {
                const int dj = i0 - 1 + j;
                const bool ok = (unsigned)dj < 16u;
                m[j] = ok ? 1.f : 0.f;
                const ushort8 v = *(const ushort8*)(cb + (size_t)(ok ? dj : 0) * 64);
#pragma unroll
                for (int e = 0; e < 8; ++e) sv[j][e] = bf2f(v[e]);   // finite data; mask in coeffs
            }
            const float fi = 1.f - fr;
            const float w0a = fi * m[0], w0b = fr * m[1];
            const float w1a = fi * m[1], w1b = fr * m[2];
            const float w2a = fi * m[2], w2b = fr * m[3];
            float a0[8], a1[8], a2[8];
#pragma unroll
            for (int e = 0; e < 8; ++e) {
                a0[e] = fmaf(sv[1][e], w0b, sv[0][e] * w0a);
                a1[e] = fmaf(sv[2][e], w1b, sv[1][e] * w1a);
                a2[e] = fmaf(sv[3][e], w2b, sv[2][e] * w2a);
            }
            p0.x = cvt_pk_bf16(a0[0], a0[1]); p0.y = cvt_pk_bf16(a0[2], a0[3]);
            p0.z = cvt_pk_bf16(a0[4], a0[5]); p0.w = cvt_pk_bf16(a0[6], a0[7]);
            p1.x = cvt_pk_bf16(a1[0], a1[1]); p1.y = cvt_pk_bf16(a1[2], a1[3]);
            p1.z = cvt_pk_bf16(a1[4], a1[5]); p1.w = cvt_pk_bf16(a1[6], a1[7]);
            p2.x = cvt_pk_bf16(a2[0], a2[1]); p2.y = cvt_pk_bf16(a2[2], a2[3]);
            p2.z = cvt_pk_bf16(a2[4], a2[5]); p2.w = cvt_pk_bf16(a2[6], a2[7]);
        }
        const int sl = hq3 * 58 + px;
        *(uint4*)&A[(size_t)(sl          ) * 72 + g * 8] = p0;   // kd=0 rows 0..2
        *(uint4*)&A[(size_t)(sl + 3 * 58 ) * 72 + g * 8] = p1;   // kd=1 rows 3..5
        *(uint4*)&A[(size_t)(sl + 6 * 58 ) * 72 + g * 8] = p2;   // kd=2 rows 6..8
    }
    __syncthreads();

    const int mf0 = (wave & 1) * 2, nf0 = wave >> 1;     // 2 mf x 1 nf per wave
    f32x4 acc[2];
    acc[0] = (f32x4){0.f, 0.f, 0.f, 0.f};
    acc[1] = (f32x4){0.f, 0.f, 0.f, 0.f};

    // ---- 27-tap K-loop, strength-reduced, B software-pipelined ----
    const unsigned short* Btb = Bt + (unsigned)nf0 * 1024;
    unsigned boff = (unsigned)lane * 8;
    short8 bc0 = *(const short8*)(Btb + boff);
    short8 bc1 = *(const short8*)(Btb + boff + 512);
    boff += 4096u;
    unsigned arow = (unsigned)(mf0 * 16 + lm) * 72 + quad * 8;

#pragma unroll 1
    for (int r9 = 0; r9 < 9; ++r9) {
#pragma unroll
        for (int kw = 0; kw < 3; ++kw) {
            const bool more = (kw < 2) | (r9 < 8);            // t < 26
            short8 bn0, bn1;
            if (more) {
                bn0 = *(const short8*)(Btb + boff);
                bn1 = *(const short8*)(Btb + boff + 512);
            }
            const unsigned ab = arow + kw * 72;
            const short8 a00 = *(const short8*)&A[ab];
            const short8 a01 = *(const short8*)&A[ab + 1152];
            const short8 a10 = *(const short8*)&A[ab + 32];
            const short8 a11 = *(const short8*)&A[ab + 1152 + 32];
            acc[0] = __builtin_amdgcn_mfma_f32_16x16x32_bf16(a00, bc0, acc[0], 0, 0, 0);
            acc[1] = __builtin_amdgcn_mfma_f32_16x16x32_bf16(a01, bc0, acc[1], 0, 0, 0);
            acc[0] = __builtin_amdgcn_mfma_f32_16x16x32_bf16(a10, bc1, acc[0], 0, 0, 0);
            acc[1] = __builtin_amdgcn_mfma_f32_16x16x32_bf16(a11, bc1, acc[1], 0, 0, 0);
            if (more) {
                bc0 = bn0; bc1 = bn1;
                boff += 4096u;
            }
        }
        arow += 58 * 72;
    }

    // ---- epilogue: bf16 tile in LDS -> coalesced ch-last stores ----
    __syncthreads();
#pragma unroll
    for (int mf = 0; mf < 2; ++mf)
#pragma unroll
        for (int r = 0; r < 4; ++r) {
            const int mm = (mf0 + mf) * 16 + quad * 4 + r;
            if (mm < 56)
                A[mm * 72 + nf0 * 16 + lm] = (unsigned short)f2bf(acc[mf][r]);
        }
    __syncthreads();
    const size_t pixb = ((size_t)(n * 16) + d) * HW + h * 56;
    if (tid < 448) {
        const int px = tid >> 3, kk = tid & 7;
        *(uint4*)(out1 + (pixb + px) * 64 + kk * 8) = *(const uint4*)&A[px * 72 + kk * 8];
    }
}

// ---------------- per-channel stats over bf16 ch-last ----------------------
__global__ __launch_bounds__(256) void k_stats_bf16(
    const unsigned short* __restrict__ src, float* __restrict__ sums, float* __restrict__ sqs)
{
    const int c4 = threadIdx.x & 15, part = threadIdx.x >> 4;   // 16 ci-quads, 16 parts
    const size_t base = (size_t)blockIdx.x * 1024;
    float s[4] = {0.f, 0.f, 0.f, 0.f}, q[4] = {0.f, 0.f, 0.f, 0.f};
#pragma unroll 4
    for (int i = 0; i < 64; ++i) {
        const size_t pix = base + part + (size_t)i * 16;
        const uint2 v = *(const uint2*)(src + pix * 64 + c4 * 4);
        const float f0 = bf2f(v.x & 0xffffu), f1 = bf2f(v.x >> 16);
        const float f2 = bf2f(v.y & 0xffffu), f3 = bf2f(v.y >> 16);
        s[0] += f0; q[0] = fmaf(f0, f0, q[0]);
        s[1] += f1; q[1] = fmaf(f1, f1, q[1]);
        s[2] += f2; q[2] = fmaf(f2, f2, q[2]);
        s[3] += f3; q[3] = fmaf(f3, f3, q[3]);
    }
    __shared__ float S[64], Q[64];
    if (threadIdx.x < 64) { S[threadIdx.x] = 0.f; Q[threadIdx.x] = 0.f; }
    __syncthreads();
#pragma unroll
    for (int e = 0; e < 4; ++e) {
        atomicAdd(&S[c4 * 4 + e], s[e]);
        atomicAdd(&Q[c4 * 4 + e], q[e]);
    }
    __syncthreads();
    if (threadIdx.x < 64) {
        atomicAdd(&sums[threadIdx.x], S[threadIdx.x]);
        atomicAdd(&sqs[threadIdx.x],  Q[threadIdx.x]);
    }
}

// ---------------- per-channel stats, NCDHW fp32 ----------------------------
__global__ __launch_bounds__(256) void k_stats(
    const float* __restrict__ src, float* __restrict__ sums, float* __restrict__ sqs)
{
    const int c = blockIdx.x, n = blockIdx.y;
    const float* p = src + ((size_t)n * 64 + c) * DHW;
    float s = 0.f, q = 0.f;
    for (int i = threadIdx.x; i < DHW; i += 256) {
        const float v = p[i];
        s += v; q = fmaf(v, v, q);
    }
    for (int o = 32; o > 0; o >>= 1) {
        s += __shfl_down(s, o);
        q += __shfl_down(q, o);
    }
    __shared__ float ls[4], lq[4];
    const int wv = threadIdx.x >> 6, lane = threadIdx.x & 63;
    if (lane == 0) { ls[wv] = s; lq[wv] = q; }
    __syncthreads();
    if (threadIdx.x == 0) {
        atomicAdd(&sums[c], ls[0] + ls[1] + ls[2] + ls[3]);
        atomicAdd(&sqs[c],  lq[0] + lq[1] + lq[2] + lq[3]);
    }
}

// ---------------- finalize BN: scale/shift ---------------------------------
__global__ void k_finalize(const float* __restrict__ sums, const float* __restrict__ sqs,
                           const float* __restrict__ gamma, const float* __restrict__ beta,
                           float* __restrict__ scale, float* __restrict__ shift)
{
    const int c = threadIdx.x; // 64 threads
    const float mean = sums[c] / CNT;
    const float var  = sqs[c] / CNT - mean * mean;
    const float sc   = gamma[c] * rsqrtf(var + 1e-5f);
    scale[c] = sc;
    shift[c] = fmaf(-mean, sc, beta[c]);
}

// -------- BN2 + residual + ReLU: dst = relu(bn(raw) + x)  (float4) ---------
__global__ __launch_bounds__(256) void k_residual(
    float4* __restrict__ dst, const float4* __restrict__ raw,
    const float4* __restrict__ x,
    const float* __restrict__ scale, const float* __restrict__ shift)
{
    const int i = blockIdx.x * 256 + threadIdx.x;   // < 6422528
    const int c = (i / 12544) & 63;                  // wave-uniform
    const float sc = scale[c], sh = shift[c];
    float4 v = raw[i];
    const float4 xv = x[i];
    v.x = fmaxf(fmaf(v.x, sc, sh) + xv.x, 0.f);
    v.y = fmaxf(fmaf(v.y, sc, sh) + xv.y, 0.f);
    v.z = fmaxf(fmaf(v.z, sc, sh) + xv.z, 0.f);
    v.w = fmaxf(fmaf(v.w, sc, sh) + xv.w, 0.f);
    dst[i] = v;
}

extern "C" void kernel_launch(void* const* d_in, const int* in_sizes, int n_in,
                              void* d_out, int out_size, void* d_ws, size_t ws_size,
                              hipStream_t stream) {
    const float* x     = (const float*)d_in[0];
    const float* w_off = (const float*)d_in[1];
    const float* b_off = (const float*)d_in[2];
    const float* w1    = (const float*)d_in[3];
    const float* w2    = (const float*)d_in[4];
    const float* b2    = (const float*)d_in[5];
    const float* g1    = (const float*)d_in[6];
    const float* be1   = (const float*)d_in[7];
    const float* g2    = (const float*)d_in[8];
    const float* be2   = (const float*)d_in[9];

    // ---- buffer plan ----
    // d_out: [0, 2*NEL) bytes      : out1 (deform result, bf16 ch-last) -- dead after k_conv<64>
    //        byte 52,000,000       : weight blocks (bf16) -- dead after k_conv<64>
    //        [4*NEL, ...) bytes    : off output (fp32, final)
    //        [0, 4*NEL) bytes      : final out (fp32), written LAST by k_residual
    // d_ws:  [0, 2*NEL) bytes      : xt (bf16 D-innermost x) -- dead after k_deform
    //        [0, 4*NEL) bytes      : raw (conv2 output fp32 NCDHW) overwrites xt
    //        [4*NEL, +2KiB)        : st stats block
    float* out     = (float*)d_out;
    float* off_out = out + NEL;
    unsigned short* out1 = (unsigned short*)d_out;
    unsigned short* wb   = (unsigned short*)(out + 13000000);  // byte 52,000,000
    unsigned short* BtO  = wb;
    unsigned short* Bt1  = BtO + 27648;
    unsigned short* Bt2  = Bt1 + 110592;

    unsigned short* xt  = (unsigned short*)d_ws;
    float*          raw = (float*)d_ws;
    float*          st  = (float*)d_ws + NEL;   // bytes [4*NEL, 4*NEL+2048)
    // st: 0 sum1 | 64 sq1 | 128 sc1 | 192 sh1 | 256 sum2 | 320 sq2 | 384 sc2 | 448 sh2

    hipMemsetAsync(st, 0, 512 * sizeof(float), stream);

    k_transpose<<<dim3(16, 8, 7), 256, 0, stream>>>(x, xt);
    k_wprep<<<432, 256, 0, stream>>>(w_off, w1, w2, BtO, Bt1, Bt2);

    const dim3 cgrid(56, 16, 8);   // h, d, n (decoded via xcd_decode inside)
    k_conv<8, false, true><<<cgrid, 256, 0, stream>>>(xt, BtO, b_off, nullptr, nullptr, off_out);
    k_deform<<<cgrid, 512, 0, stream>>>(xt, off_out, Bt1, out1);

    k_stats_bf16<<<392, 256, 0, stream>>>(out1, st + 0, st + 64);
    k_finalize<<<1, 64, 0, stream>>>(st + 0, st + 64, g1, be1, st + 128, st + 192);

    k_conv<64, true, false><<<cgrid, 512, 0, stream>>>(out1, Bt2, b2, st + 128, st + 192, raw);

    k_stats<<<dim3(64, 8), 256, 0, stream>>>(raw, st + 256, st + 320);
    k_finalize<<<1, 64, 0, stream>>>(st + 256, st + 320, g2, be2, st + 384, st + 448);
    k_residual<<<25088, 256, 0, stream>>>((float4*)out, (const float4*)raw, (const float4*)x, st + 384, st + 448);
}